// Round 5
// baseline (615.852 us; speedup 1.0000x reference)
//
#include <hip/hip_runtime.h>
#include <math.h>

// Graph normalizing flow on MI355X.
// State x (N x 128) fp32 lives in d_out; bf16 mirror xb for propagation gathers.
// ldj at d_out[N*128]. CSR-by-destination gather (packed col+weight uint2).
// A(hW)=(Ah)W rewrite: s/t GCN layer-0 share one 64-feat propagation.
// Dense layers: bf16 MFMA GEMMs, LDS-staged epilogues -> coalesced float4/uint4 I/O.
// Propagation: one WAVE per node (uniform bounds), lanes = edge-slot x feat-chunk.

typedef __attribute__((ext_vector_type(8))) short bf16x8;
typedef __attribute__((ext_vector_type(4))) float f32x4;

__device__ __forceinline__ float bf_lo(unsigned int u) { return __uint_as_float(u << 16); }
__device__ __forceinline__ float bf_hi(unsigned int u) { return __uint_as_float(u & 0xffff0000u); }
__device__ __forceinline__ unsigned short f2bf(float f) {
  unsigned int u = __float_as_uint(f);
  u = (u + 0x7fffu + ((u >> 16) & 1u)) >> 16;  // round-to-nearest-even
  return (unsigned short)u;
}
__device__ __forceinline__ unsigned int pack2(float a, float b) {
  return (unsigned int)f2bf(a) | ((unsigned int)f2bf(b) << 16);
}

__global__ void init_out_kernel(const float* __restrict__ x, float* __restrict__ out,
                                unsigned short* __restrict__ xb, int total) {
  int i = blockIdx.x * blockDim.x + threadIdx.x;
  if (i < total) {
    float v = x[i];
    out[i] = v;
    xb[i] = f2bf(v);
  }
  if (i == 0) out[total] = 0.f;  // ldj accumulator
}

__global__ void meta_init_kernel(int* cnt, int* fill, int n) {
  int i = blockIdx.x * blockDim.x + threadIdx.x;
  if (i < n) { cnt[i] = 1; fill[i] = 0; }  // cnt starts at 1: self-loop
}

__global__ void count_kernel(const int* __restrict__ dst, int* cnt, int e) {
  int i = blockIdx.x * blockDim.x + threadIdx.x;
  if (i < e) atomicAdd(&cnt[dst[i]], 1);
}

__global__ void dinv_kernel(const int* __restrict__ cnt, float* __restrict__ dinv, int n) {
  int i = blockIdx.x * blockDim.x + threadIdx.x;
  if (i < n) dinv[i] = rsqrtf(fmaxf((float)cnt[i], 1.f));
}

// --- parallel exclusive scan: per-block scan -> scan block sums -> add offsets ---
__global__ void scan_blk_kernel(const int* __restrict__ cnt, int* __restrict__ row_ptr,
                                int* __restrict__ bsum, int n) {
  __shared__ int sdata[1024];
  int tid = threadIdx.x;
  int i = blockIdx.x * 1024 + tid;
  int v = (i < n) ? cnt[i] : 0;
  sdata[tid] = v;
  __syncthreads();
  for (int d = 1; d < 1024; d <<= 1) {
    int t = (tid >= d) ? sdata[tid - d] : 0;
    __syncthreads();
    sdata[tid] += t;
    __syncthreads();
  }
  if (i < n) row_ptr[i] = sdata[tid] - v;  // exclusive within block
  if (tid == 1023) bsum[blockIdx.x] = sdata[1023];
}

__global__ void scan_top_kernel(int* __restrict__ bsum, int nb) {
  __shared__ int sdata[1024];
  int tid = threadIdx.x;
  int v = (tid < nb) ? bsum[tid] : 0;
  sdata[tid] = v;
  __syncthreads();
  for (int d = 1; d < 1024; d <<= 1) {
    int t = (tid >= d) ? sdata[tid - d] : 0;
    __syncthreads();
    sdata[tid] += t;
    __syncthreads();
  }
  if (tid < nb) bsum[tid] = sdata[tid] - v;  // exclusive block offsets
}

__global__ void scan_add_kernel(int* __restrict__ row_ptr, const int* __restrict__ bsum,
                                int n, int m) {
  int i = blockIdx.x * blockDim.x + threadIdx.x;
  if (i < n) row_ptr[i] += bsum[i >> 10];
  if (i == 0) row_ptr[n] = m;
}

// One 8B store per edge: cw[pos] = {col, bits(weight)}
__global__ void fill_kernel(const int* __restrict__ src, const int* __restrict__ dst,
                            const float* __restrict__ dinv, const int* __restrict__ row_ptr,
                            int* fill, uint2* __restrict__ cw, int e, int n) {
  int i = blockIdx.x * blockDim.x + threadIdx.x;
  if (i < e) {
    int s = src[i], d = dst[i];
    int pos = row_ptr[d] + atomicAdd(&fill[d], 1);
    cw[pos] = make_uint2((unsigned)s, __float_as_uint(dinv[s] * dinv[d]));
  } else if (i < e + n) {
    int v = i - e;
    int pos = row_ptr[v] + atomicAdd(&fill[v], 1);
    float dv = dinv[v];
    cw[pos] = make_uint2((unsigned)v, __float_as_uint(dv * dv));
  }
}

// Build bf16 transposed weight mats + fp32 bias vectors for all 4 half-steps.
__global__ void prep_weights(const float* __restrict__ W, const float* __restrict__ B,
                             unsigned short* __restrict__ WT0, unsigned short* __restrict__ WT1,
                             float* __restrict__ b0c, float* __restrict__ b1c) {
  int idx = blockIdx.x * blockDim.x + threadIdx.x;
  if (idx < 65536) {
    int hsi = idx >> 14;
    int lay = (idx >> 13) & 1;
    int j = (idx >> 6) & 127;
    int k = idx & 63;
    int i = hsi >> 1, half = hsi & 1;
    int g = half * 4 + (j < 64 ? 0 : 2) + i;
    float v = W[(((size_t)g * 2 + lay) * 64 + k) * 64 + (j & 63)];
    unsigned short* dst = lay ? WT1 : WT0;
    dst[(size_t)hsi * 8192 + j * 64 + k] = f2bf(v);
  }
  if (idx < 1024) {
    int hsi = idx >> 8;
    int lay = (idx >> 7) & 1;
    int j = idx & 127;
    int i = hsi >> 1, half = hsi & 1;
    int g = half * 4 + (j < 64 ? 0 : 2) + i;
    (lay ? b1c : b0c)[hsi * 128 + j] = B[(g * 2 + lay) * 64 + (j & 63)];
  }
}

// One wave per node. UPN = uint2-chunks per row (16 -> 64 feats, 32 -> 128 feats).
// Lanes: eo = edge slot (64/UPN slots), li = uint2 index. Wave-uniform loop bounds.
// 4-way edge unroll -> 4 independent 8B gathers in flight per thread.
template <int UPN>
__global__ void propagate_kernel(const unsigned int* __restrict__ X, int ldu, int xoffu,
                                 unsigned int* __restrict__ Y, int ldyu,
                                 const int* __restrict__ row_ptr, const uint2* __restrict__ cw,
                                 int n) {
  constexpr int EPG = 64 / UPN;  // edge slots per wave
  int wid = (blockIdx.x * blockDim.x + threadIdx.x) >> 6;
  if (wid >= n) return;
  int lane = threadIdx.x & 63;
  int eo = lane / UPN;
  int li = lane % UPN;
  int beg = row_ptr[wid], end = row_ptr[wid + 1];
  float a0 = 0.f, a1 = 0.f, a2 = 0.f, a3 = 0.f;
  int i = beg + eo;
  for (; i + 3 * EPG < end; i += 4 * EPG) {
    uint2 e0 = cw[i], e1 = cw[i + EPG], e2 = cw[i + 2 * EPG], e3 = cw[i + 3 * EPG];
    float w0 = __uint_as_float(e0.y), w1 = __uint_as_float(e1.y);
    float w2 = __uint_as_float(e2.y), w3 = __uint_as_float(e3.y);
    uint2 u0 = *((const uint2*)(X + (size_t)e0.x * ldu + xoffu) + li);
    uint2 u1 = *((const uint2*)(X + (size_t)e1.x * ldu + xoffu) + li);
    uint2 u2 = *((const uint2*)(X + (size_t)e2.x * ldu + xoffu) + li);
    uint2 u3 = *((const uint2*)(X + (size_t)e3.x * ldu + xoffu) + li);
    a0 += w0 * bf_lo(u0.x); a1 += w0 * bf_hi(u0.x); a2 += w0 * bf_lo(u0.y); a3 += w0 * bf_hi(u0.y);
    a0 += w1 * bf_lo(u1.x); a1 += w1 * bf_hi(u1.x); a2 += w1 * bf_lo(u1.y); a3 += w1 * bf_hi(u1.y);
    a0 += w2 * bf_lo(u2.x); a1 += w2 * bf_hi(u2.x); a2 += w2 * bf_lo(u2.y); a3 += w2 * bf_hi(u2.y);
    a0 += w3 * bf_lo(u3.x); a1 += w3 * bf_hi(u3.x); a2 += w3 * bf_lo(u3.y); a3 += w3 * bf_hi(u3.y);
  }
  for (; i < end; i += EPG) {
    uint2 e0 = cw[i];
    float w = __uint_as_float(e0.y);
    uint2 u = *((const uint2*)(X + (size_t)e0.x * ldu + xoffu) + li);
    a0 += w * bf_lo(u.x); a1 += w * bf_hi(u.x); a2 += w * bf_lo(u.y); a3 += w * bf_hi(u.y);
  }
#pragma unroll
  for (int ms = UPN; ms < 64; ms <<= 1) {
    a0 += __shfl_xor(a0, ms);
    a1 += __shfl_xor(a1, ms);
    a2 += __shfl_xor(a2, ms);
    a3 += __shfl_xor(a3, ms);
  }
  if (lane < UPN) {
    uint2 r;
    r.x = pack2(a0, a1);
    r.y = pack2(a2, a3);
    *((uint2*)(Y + (size_t)wid * ldyu) + li) = r;
  }
}

// h1[r][j] = bf16(relu(p[r] @ Wcat0 + b0cat)). Phase1: MFMA -> LDS (bf16 tile).
// Phase2: coalesced uint4 write-out of 64x128 bf16 tile.
__global__ __launch_bounds__(256) void gemm_layer0(const unsigned short* __restrict__ P,
                                                   const unsigned short* __restrict__ WT,
                                                   const float* __restrict__ bc,
                                                   unsigned short* __restrict__ H1, int n) {
  __shared__ unsigned short cs[64][136];  // 272B rows: 16B-aligned, 2-way max conflicts
  int w = threadIdx.x >> 6, l = threadIdx.x & 63;
  int rbase0 = blockIdx.x * 64;
  int lr = l & 15, kg = l >> 4;
  int arow = rbase0 + w * 16 + lr;
  if (arow >= n) arow = n - 1;  // clamp; result discarded by guarded store
  const bf16x8* ap = (const bf16x8*)(P + (size_t)arow * 64);
  bf16x8 a0 = ap[kg];
  bf16x8 a1 = ap[kg + 4];
  f32x4 acc[8];
#pragma unroll
  for (int ct = 0; ct < 8; ++ct) {
    const bf16x8* bp = (const bf16x8*)(WT + (size_t)(ct * 16 + lr) * 64);
    f32x4 c = {0.f, 0.f, 0.f, 0.f};
    c = __builtin_amdgcn_mfma_f32_16x16x32_bf16(a0, bp[kg], c, 0, 0, 0);
    c = __builtin_amdgcn_mfma_f32_16x16x32_bf16(a1, bp[kg + 4], c, 0, 0, 0);
    acc[ct] = c;
  }
#pragma unroll
  for (int ct = 0; ct < 8; ++ct) {
    int colj = ct * 16 + lr;
    float bb = bc[colj];
#pragma unroll
    for (int i2 = 0; i2 < 4; ++i2) {
      int lrow = w * 16 + kg * 4 + i2;  // C/D: col=lane&15, row=(lane>>4)*4+reg
      cs[lrow][colj] = f2bf(fmaxf(acc[ct][i2] + bb, 0.f));
    }
  }
  __syncthreads();
  int row = threadIdx.x >> 2;
  int cbase = (threadIdx.x & 3) * 32;
  if (rbase0 + row < n) {
    uint4* dstp = (uint4*)(H1 + (size_t)(rbase0 + row) * 128 + cbase);
#pragma unroll
    for (int ci = 0; ci < 4; ++ci) dstp[ci] = *(const uint4*)(&cs[row][cbase + ci * 8]);
  }
}

// s=sigmoid(q[:,:64]@Ws1+bs), t=sigmoid(q[:,64:]@Wt1+bt).
// Phase1: MFMA + sigmoid -> LDS exp(s), t tiles; ldj += sum(s).
// Phase2: coalesced float4 RMW of Xout half + uint2 bf16-mirror stores.
__global__ __launch_bounds__(256) void gemm_final(const unsigned short* __restrict__ Q,
                                                  const unsigned short* __restrict__ WT,
                                                  const float* __restrict__ bc,
                                                  float* __restrict__ Xout,
                                                  unsigned short* __restrict__ Xb, int xoff,
                                                  float* __restrict__ ldj, int n) {
  __shared__ float es[64][68];  // exp(s); 272B rows
  __shared__ float tv[64][68];  // t
  int w = threadIdx.x >> 6, l = threadIdx.x & 63;
  int rbase0 = blockIdx.x * 64;
  int lr = l & 15, kg = l >> 4;
  int arow = rbase0 + w * 16 + lr;
  if (arow >= n) arow = n - 1;
  const bf16x8* ap = (const bf16x8*)(Q + (size_t)arow * 128);
  bf16x8 as0 = ap[kg], as1 = ap[kg + 4];
  bf16x8 at0 = ap[kg + 8], at1 = ap[kg + 12];
  f32x4 acc[8];
#pragma unroll
  for (int ct = 0; ct < 8; ++ct) {
    const bf16x8* bp = (const bf16x8*)(WT + (size_t)(ct * 16 + lr) * 64);
    f32x4 c = {0.f, 0.f, 0.f, 0.f};
    bf16x8 x0 = (ct < 4) ? as0 : at0;
    bf16x8 x1 = (ct < 4) ? as1 : at1;
    c = __builtin_amdgcn_mfma_f32_16x16x32_bf16(x0, bp[kg], c, 0, 0, 0);
    c = __builtin_amdgcn_mfma_f32_16x16x32_bf16(x1, bp[kg + 4], c, 0, 0, 0);
    acc[ct] = c;
  }
  float wldj = 0.f;
#pragma unroll
  for (int ct = 0; ct < 4; ++ct) {
    int colj = ct * 16 + lr;
    float bs = bc[colj], bt = bc[colj + 64];
#pragma unroll
    for (int i2 = 0; i2 < 4; ++i2) {
      int lrow = w * 16 + kg * 4 + i2;
      float sv = 1.f / (1.f + __expf(-(acc[ct][i2] + bs)));
      float tvv = 1.f / (1.f + __expf(-(acc[ct + 4][i2] + bt)));
      es[lrow][colj] = __expf(sv);
      tv[lrow][colj] = tvv;
      if (rbase0 + lrow < n) wldj += sv;
    }
  }
#pragma unroll
  for (int off2 = 32; off2 > 0; off2 >>= 1) wldj += __shfl_down(wldj, off2);
  if (l == 0) atomicAdd(ldj, wldj);
  __syncthreads();
  int row = threadIdx.x >> 2;
  int c0 = (threadIdx.x & 3) * 16;
  int grow = rbase0 + row;
  if (grow < n) {
    size_t base = (size_t)grow * 128 + xoff;
#pragma unroll
    for (int ci = 0; ci < 4; ++ci) {
      int c = c0 + ci * 4;
      float4 xv = *(const float4*)(Xout + base + c);
      float4 nv;
      nv.x = xv.x * es[row][c + 0] + tv[row][c + 0];
      nv.y = xv.y * es[row][c + 1] + tv[row][c + 1];
      nv.z = xv.z * es[row][c + 2] + tv[row][c + 2];
      nv.w = xv.w * es[row][c + 3] + tv[row][c + 3];
      *(float4*)(Xout + base + c) = nv;
      uint2 bb;
      bb.x = pack2(nv.x, nv.y);
      bb.y = pack2(nv.z, nv.w);
      *(uint2*)(Xb + base + c) = bb;
    }
  }
}

extern "C" void kernel_launch(void* const* d_in, const int* in_sizes, int n_in,
                              void* d_out, int out_size, void* d_ws, size_t ws_size,
                              hipStream_t stream) {
  const float* x = (const float*)d_in[0];
  const int* eidx = (const int*)d_in[1];
  const float* W = (const float*)d_in[2];
  const float* B = (const float*)d_in[3];
  float* out = (float*)d_out;

  int n = in_sizes[0] / 128;
  int e = in_sizes[1] / 2;
  int m = e + n;
  const int* src = eidx;
  const int* dstv = eidx + e;

  size_t off = 0;
  auto alloc = [&](size_t bytes) {
    size_t r = off;
    off += (bytes + 255) & ~(size_t)255;
    return r;
  };
  char* ws = (char*)d_ws;
  int* cnt = (int*)(ws + alloc((size_t)n * 4));
  int* fill = (int*)(ws + alloc((size_t)n * 4));
  int* row_ptr = (int*)(ws + alloc((size_t)(n + 1) * 4));
  int* bsum = (int*)(ws + alloc((size_t)1024 * 4));
  float* dinv = (float*)(ws + alloc((size_t)n * 4));
  uint2* cw = (uint2*)(ws + alloc((size_t)m * 8));
  unsigned short* p = (unsigned short*)(ws + alloc((size_t)n * 64 * 2));    // bf16 A*x_in
  unsigned short* h1 = (unsigned short*)(ws + alloc((size_t)n * 128 * 2));  // bf16 hidden
  unsigned short* q = (unsigned short*)(ws + alloc((size_t)n * 128 * 2));   // bf16 A*h1
  unsigned short* xb = (unsigned short*)(ws + alloc((size_t)n * 128 * 2));  // bf16 state mirror
  unsigned short* wt0 = (unsigned short*)(ws + alloc((size_t)4 * 8192 * 2));
  unsigned short* wt1 = (unsigned short*)(ws + alloc((size_t)4 * 8192 * 2));
  float* b0c = (float*)(ws + alloc((size_t)4 * 128 * 4));
  float* b1c = (float*)(ws + alloc((size_t)4 * 128 * 4));

  int total = n * 128;
  int nb = (n + 1023) / 1024;
  init_out_kernel<<<(total + 256) / 256, 256, 0, stream>>>(x, out, xb, total);
  meta_init_kernel<<<(n + 255) / 256, 256, 0, stream>>>(cnt, fill, n);
  count_kernel<<<(e + 255) / 256, 256, 0, stream>>>(dstv, cnt, e);
  dinv_kernel<<<(n + 255) / 256, 256, 0, stream>>>(cnt, dinv, n);
  scan_blk_kernel<<<nb, 1024, 0, stream>>>(cnt, row_ptr, bsum, n);
  scan_top_kernel<<<1, 1024, 0, stream>>>(bsum, nb);
  scan_add_kernel<<<(n + 255) / 256, 256, 0, stream>>>(row_ptr, bsum, n, m);
  fill_kernel<<<(m + 255) / 256, 256, 0, stream>>>(src, dstv, dinv, row_ptr, fill, cw, e, n);
  prep_weights<<<256, 256, 0, stream>>>(W, B, wt0, wt1, b0c, b1c);

  float* ldj = out + total;
  const int hs_xin[4] = {0, 64, 0, 64};
  int gblk = (n + 63) / 64;
  int pgrid = (n * 64 + 255) / 256;  // one wave per node
  for (int hsi = 0; hsi < 4; ++hsi) {
    int xin = hs_xin[hsi];
    int xout = 64 - xin;
    // p = A * x_in (64 feats from bf16 mirror)
    propagate_kernel<16><<<pgrid, 256, 0, stream>>>(
        (const unsigned int*)xb, 64, xin / 2, (unsigned int*)p, 32, row_ptr, cw, n);
    gemm_layer0<<<gblk, 256, 0, stream>>>(p, wt0 + (size_t)hsi * 8192, b0c + hsi * 128, h1, n);
    // q = A * h1 (128 feats)
    propagate_kernel<32><<<pgrid, 256, 0, stream>>>(
        (const unsigned int*)h1, 64, 0, (unsigned int*)q, 64, row_ptr, cw, n);
    gemm_final<<<gblk, 256, 0, stream>>>(q, wt1 + (size_t)hsi * 8192, b1c + hsi * 128, out, xb,
                                         xout, ldj, n);
  }
}

// Round 6
// 480.614 us; speedup vs baseline: 1.2814x; 1.2814x over previous
//
#include <hip/hip_runtime.h>
#include <math.h>

// Graph normalizing flow on MI355X.
// State x (N x 128) fp32 lives in d_out; bf16 mirror xb for propagation gathers.
// ldj at d_out[N*128]. CSR-by-destination gather (packed col+weight uint2).
// A(hW)=(Ah)W rewrite: s/t GCN layer-0 share one 64-feat propagation.
// Dense layers: bf16 MFMA GEMMs, LDS-staged epilogues -> coalesced float4/uint4 I/O.
// ldj: per-block non-atomic partials + one deterministic reduce kernel
// (per-wave atomicAdd to a single address serialized at ~17ns each = 53us/dispatch).

typedef __attribute__((ext_vector_type(8))) short bf16x8;
typedef __attribute__((ext_vector_type(4))) float f32x4;

__device__ __forceinline__ float bf_lo(unsigned int u) { return __uint_as_float(u << 16); }
__device__ __forceinline__ float bf_hi(unsigned int u) { return __uint_as_float(u & 0xffff0000u); }
__device__ __forceinline__ unsigned short f2bf(float f) {
  unsigned int u = __float_as_uint(f);
  u = (u + 0x7fffu + ((u >> 16) & 1u)) >> 16;  // round-to-nearest-even
  return (unsigned short)u;
}
__device__ __forceinline__ unsigned int pack2(float a, float b) {
  return (unsigned int)f2bf(a) | ((unsigned int)f2bf(b) << 16);
}

__global__ void init_out_kernel(const float* __restrict__ x, float* __restrict__ out,
                                unsigned short* __restrict__ xb, int total) {
  int i = blockIdx.x * blockDim.x + threadIdx.x;
  if (i < total) {
    float v = x[i];
    out[i] = v;
    xb[i] = f2bf(v);
  }
}

__global__ void meta_init_kernel(int* cnt, int* fill, int n) {
  int i = blockIdx.x * blockDim.x + threadIdx.x;
  if (i < n) { cnt[i] = 1; fill[i] = 0; }  // cnt starts at 1: self-loop
}

__global__ void count_kernel(const int* __restrict__ dst, int* cnt, int e) {
  int i = blockIdx.x * blockDim.x + threadIdx.x;
  if (i < e) atomicAdd(&cnt[dst[i]], 1);
}

__global__ void dinv_kernel(const int* __restrict__ cnt, float* __restrict__ dinv, int n) {
  int i = blockIdx.x * blockDim.x + threadIdx.x;
  if (i < n) dinv[i] = rsqrtf(fmaxf((float)cnt[i], 1.f));
}

// --- parallel exclusive scan: per-block scan -> scan block sums -> add offsets ---
__global__ void scan_blk_kernel(const int* __restrict__ cnt, int* __restrict__ row_ptr,
                                int* __restrict__ bsum, int n) {
  __shared__ int sdata[1024];
  int tid = threadIdx.x;
  int i = blockIdx.x * 1024 + tid;
  int v = (i < n) ? cnt[i] : 0;
  sdata[tid] = v;
  __syncthreads();
  for (int d = 1; d < 1024; d <<= 1) {
    int t = (tid >= d) ? sdata[tid - d] : 0;
    __syncthreads();
    sdata[tid] += t;
    __syncthreads();
  }
  if (i < n) row_ptr[i] = sdata[tid] - v;  // exclusive within block
  if (tid == 1023) bsum[blockIdx.x] = sdata[1023];
}

__global__ void scan_top_kernel(int* __restrict__ bsum, int nb) {
  __shared__ int sdata[1024];
  int tid = threadIdx.x;
  int v = (tid < nb) ? bsum[tid] : 0;
  sdata[tid] = v;
  __syncthreads();
  for (int d = 1; d < 1024; d <<= 1) {
    int t = (tid >= d) ? sdata[tid - d] : 0;
    __syncthreads();
    sdata[tid] += t;
    __syncthreads();
  }
  if (tid < nb) bsum[tid] = sdata[tid] - v;  // exclusive block offsets
}

__global__ void scan_add_kernel(int* __restrict__ row_ptr, const int* __restrict__ bsum,
                                int n, int m) {
  int i = blockIdx.x * blockDim.x + threadIdx.x;
  if (i < n) row_ptr[i] += bsum[i >> 10];
  if (i == 0) row_ptr[n] = m;
}

// One 8B store per edge: cw[pos] = {col, bits(weight)}
__global__ void fill_kernel(const int* __restrict__ src, const int* __restrict__ dst,
                            const float* __restrict__ dinv, const int* __restrict__ row_ptr,
                            int* fill, uint2* __restrict__ cw, int e, int n) {
  int i = blockIdx.x * blockDim.x + threadIdx.x;
  if (i < e) {
    int s = src[i], d = dst[i];
    int pos = row_ptr[d] + atomicAdd(&fill[d], 1);
    cw[pos] = make_uint2((unsigned)s, __float_as_uint(dinv[s] * dinv[d]));
  } else if (i < e + n) {
    int v = i - e;
    int pos = row_ptr[v] + atomicAdd(&fill[v], 1);
    float dv = dinv[v];
    cw[pos] = make_uint2((unsigned)v, __float_as_uint(dv * dv));
  }
}

// Build bf16 transposed weight mats + fp32 bias vectors for all 4 half-steps.
__global__ void prep_weights(const float* __restrict__ W, const float* __restrict__ B,
                             unsigned short* __restrict__ WT0, unsigned short* __restrict__ WT1,
                             float* __restrict__ b0c, float* __restrict__ b1c) {
  int idx = blockIdx.x * blockDim.x + threadIdx.x;
  if (idx < 65536) {
    int hsi = idx >> 14;
    int lay = (idx >> 13) & 1;
    int j = (idx >> 6) & 127;
    int k = idx & 63;
    int i = hsi >> 1, half = hsi & 1;
    int g = half * 4 + (j < 64 ? 0 : 2) + i;
    float v = W[(((size_t)g * 2 + lay) * 64 + k) * 64 + (j & 63)];
    unsigned short* dst = lay ? WT1 : WT0;
    dst[(size_t)hsi * 8192 + j * 64 + k] = f2bf(v);
  }
  if (idx < 1024) {
    int hsi = idx >> 8;
    int lay = (idx >> 7) & 1;
    int j = idx & 127;
    int i = hsi >> 1, half = hsi & 1;
    int g = half * 4 + (j < 64 ? 0 : 2) + i;
    (lay ? b1c : b0c)[hsi * 128 + j] = B[(g * 2 + lay) * 64 + (j & 63)];
  }
}

// One wave per node. UPN = uint2-chunks per row (16 -> 64 feats, 32 -> 128 feats).
// Lanes: eo = edge slot (64/UPN slots), li = uint2 index. Wave-uniform loop bounds.
// 4-way edge unroll -> 4 independent 8B gathers in flight per thread.
template <int UPN>
__global__ void propagate_kernel(const unsigned int* __restrict__ X, int ldu, int xoffu,
                                 unsigned int* __restrict__ Y, int ldyu,
                                 const int* __restrict__ row_ptr, const uint2* __restrict__ cw,
                                 int n) {
  constexpr int EPG = 64 / UPN;  // edge slots per wave
  int wid = (blockIdx.x * blockDim.x + threadIdx.x) >> 6;
  if (wid >= n) return;
  int lane = threadIdx.x & 63;
  int eo = lane / UPN;
  int li = lane % UPN;
  int beg = row_ptr[wid], end = row_ptr[wid + 1];
  float a0 = 0.f, a1 = 0.f, a2 = 0.f, a3 = 0.f;
  int i = beg + eo;
  for (; i + 3 * EPG < end; i += 4 * EPG) {
    uint2 e0 = cw[i], e1 = cw[i + EPG], e2 = cw[i + 2 * EPG], e3 = cw[i + 3 * EPG];
    float w0 = __uint_as_float(e0.y), w1 = __uint_as_float(e1.y);
    float w2 = __uint_as_float(e2.y), w3 = __uint_as_float(e3.y);
    uint2 u0 = *((const uint2*)(X + (size_t)e0.x * ldu + xoffu) + li);
    uint2 u1 = *((const uint2*)(X + (size_t)e1.x * ldu + xoffu) + li);
    uint2 u2 = *((const uint2*)(X + (size_t)e2.x * ldu + xoffu) + li);
    uint2 u3 = *((const uint2*)(X + (size_t)e3.x * ldu + xoffu) + li);
    a0 += w0 * bf_lo(u0.x); a1 += w0 * bf_hi(u0.x); a2 += w0 * bf_lo(u0.y); a3 += w0 * bf_hi(u0.y);
    a0 += w1 * bf_lo(u1.x); a1 += w1 * bf_hi(u1.x); a2 += w1 * bf_lo(u1.y); a3 += w1 * bf_hi(u1.y);
    a0 += w2 * bf_lo(u2.x); a1 += w2 * bf_hi(u2.x); a2 += w2 * bf_lo(u2.y); a3 += w2 * bf_hi(u2.y);
    a0 += w3 * bf_lo(u3.x); a1 += w3 * bf_hi(u3.x); a2 += w3 * bf_lo(u3.y); a3 += w3 * bf_hi(u3.y);
  }
  for (; i < end; i += EPG) {
    uint2 e0 = cw[i];
    float w = __uint_as_float(e0.y);
    uint2 u = *((const uint2*)(X + (size_t)e0.x * ldu + xoffu) + li);
    a0 += w * bf_lo(u.x); a1 += w * bf_hi(u.x); a2 += w * bf_lo(u.y); a3 += w * bf_hi(u.y);
  }
#pragma unroll
  for (int ms = UPN; ms < 64; ms <<= 1) {
    a0 += __shfl_xor(a0, ms);
    a1 += __shfl_xor(a1, ms);
    a2 += __shfl_xor(a2, ms);
    a3 += __shfl_xor(a3, ms);
  }
  if (lane < UPN) {
    uint2 r;
    r.x = pack2(a0, a1);
    r.y = pack2(a2, a3);
    *((uint2*)(Y + (size_t)wid * ldyu) + li) = r;
  }
}

// h1[r][j] = bf16(relu(p[r] @ Wcat0 + b0cat)). Phase1: MFMA -> LDS (bf16 tile).
// Phase2: coalesced uint4 write-out of 64x128 bf16 tile.
__global__ __launch_bounds__(256) void gemm_layer0(const unsigned short* __restrict__ P,
                                                   const unsigned short* __restrict__ WT,
                                                   const float* __restrict__ bc,
                                                   unsigned short* __restrict__ H1, int n) {
  __shared__ unsigned short cs[64][136];
  int w = threadIdx.x >> 6, l = threadIdx.x & 63;
  int rbase0 = blockIdx.x * 64;
  int lr = l & 15, kg = l >> 4;
  int arow = rbase0 + w * 16 + lr;
  if (arow >= n) arow = n - 1;  // clamp; result discarded by guarded store
  const bf16x8* ap = (const bf16x8*)(P + (size_t)arow * 64);
  bf16x8 a0 = ap[kg];
  bf16x8 a1 = ap[kg + 4];
  f32x4 acc[8];
#pragma unroll
  for (int ct = 0; ct < 8; ++ct) {
    const bf16x8* bp = (const bf16x8*)(WT + (size_t)(ct * 16 + lr) * 64);
    f32x4 c = {0.f, 0.f, 0.f, 0.f};
    c = __builtin_amdgcn_mfma_f32_16x16x32_bf16(a0, bp[kg], c, 0, 0, 0);
    c = __builtin_amdgcn_mfma_f32_16x16x32_bf16(a1, bp[kg + 4], c, 0, 0, 0);
    acc[ct] = c;
  }
#pragma unroll
  for (int ct = 0; ct < 8; ++ct) {
    int colj = ct * 16 + lr;
    float bb = bc[colj];
#pragma unroll
    for (int i2 = 0; i2 < 4; ++i2) {
      int lrow = w * 16 + kg * 4 + i2;  // C/D: col=lane&15, row=(lane>>4)*4+reg
      cs[lrow][colj] = f2bf(fmaxf(acc[ct][i2] + bb, 0.f));
    }
  }
  __syncthreads();
  int row = threadIdx.x >> 2;
  int cbase = (threadIdx.x & 3) * 32;
  if (rbase0 + row < n) {
    uint4* dstp = (uint4*)(H1 + (size_t)(rbase0 + row) * 128 + cbase);
#pragma unroll
    for (int ci = 0; ci < 4; ++ci) dstp[ci] = *(const uint4*)(&cs[row][cbase + ci * 8]);
  }
}

// s=sigmoid(q[:,:64]@Ws1+bs), t=sigmoid(q[:,64:]@Wt1+bt).
// Phase1: MFMA + sigmoid -> LDS exp(s), t tiles; per-block ldj partial (NO atomics).
// Phase2: coalesced float4 RMW of Xout half + uint2 bf16-mirror stores.
__global__ __launch_bounds__(256) void gemm_final(const unsigned short* __restrict__ Q,
                                                  const unsigned short* __restrict__ WT,
                                                  const float* __restrict__ bc,
                                                  float* __restrict__ Xout,
                                                  unsigned short* __restrict__ Xb, int xoff,
                                                  float* __restrict__ partials, int n) {
  __shared__ float es[64][68];
  __shared__ float tv[64][68];
  __shared__ float redbuf[4];
  int w = threadIdx.x >> 6, l = threadIdx.x & 63;
  int rbase0 = blockIdx.x * 64;
  int lr = l & 15, kg = l >> 4;
  int arow = rbase0 + w * 16 + lr;
  if (arow >= n) arow = n - 1;
  const bf16x8* ap = (const bf16x8*)(Q + (size_t)arow * 128);
  bf16x8 as0 = ap[kg], as1 = ap[kg + 4];
  bf16x8 at0 = ap[kg + 8], at1 = ap[kg + 12];
  f32x4 acc[8];
#pragma unroll
  for (int ct = 0; ct < 8; ++ct) {
    const bf16x8* bp = (const bf16x8*)(WT + (size_t)(ct * 16 + lr) * 64);
    f32x4 c = {0.f, 0.f, 0.f, 0.f};
    bf16x8 x0 = (ct < 4) ? as0 : at0;
    bf16x8 x1 = (ct < 4) ? as1 : at1;
    c = __builtin_amdgcn_mfma_f32_16x16x32_bf16(x0, bp[kg], c, 0, 0, 0);
    c = __builtin_amdgcn_mfma_f32_16x16x32_bf16(x1, bp[kg + 4], c, 0, 0, 0);
    acc[ct] = c;
  }
  float wldj = 0.f;
#pragma unroll
  for (int ct = 0; ct < 4; ++ct) {
    int colj = ct * 16 + lr;
    float bs = bc[colj], bt = bc[colj + 64];
#pragma unroll
    for (int i2 = 0; i2 < 4; ++i2) {
      int lrow = w * 16 + kg * 4 + i2;
      float sv = 1.f / (1.f + __expf(-(acc[ct][i2] + bs)));
      float tvv = 1.f / (1.f + __expf(-(acc[ct + 4][i2] + bt)));
      es[lrow][colj] = __expf(sv);
      tv[lrow][colj] = tvv;
      if (rbase0 + lrow < n) wldj += sv;
    }
  }
#pragma unroll
  for (int off2 = 32; off2 > 0; off2 >>= 1) wldj += __shfl_down(wldj, off2);
  if (l == 0) redbuf[w] = wldj;
  __syncthreads();
  if (threadIdx.x == 0)
    partials[blockIdx.x] = redbuf[0] + redbuf[1] + redbuf[2] + redbuf[3];
  int row = threadIdx.x >> 2;
  int c0 = (threadIdx.x & 3) * 16;
  int grow = rbase0 + row;
  if (grow < n) {
    size_t base = (size_t)grow * 128 + xoff;
#pragma unroll
    for (int ci = 0; ci < 4; ++ci) {
      int c = c0 + ci * 4;
      float4 xv = *(const float4*)(Xout + base + c);
      float4 nv;
      nv.x = xv.x * es[row][c + 0] + tv[row][c + 0];
      nv.y = xv.y * es[row][c + 1] + tv[row][c + 1];
      nv.z = xv.z * es[row][c + 2] + tv[row][c + 2];
      nv.w = xv.w * es[row][c + 3] + tv[row][c + 3];
      *(float4*)(Xout + base + c) = nv;
      uint2 bb;
      bb.x = pack2(nv.x, nv.y);
      bb.y = pack2(nv.z, nv.w);
      *(uint2*)(Xb + base + c) = bb;
    }
  }
}

// Deterministic single-block sum of np partials -> *ldj_out (overwrite).
__global__ void ldj_reduce_kernel(const float* __restrict__ partials, int np,
                                  float* __restrict__ ldj_out) {
  __shared__ float sdata[1024];
  int tid = threadIdx.x;
  float a = 0.f;
  for (int i = tid; i < np; i += 1024) a += partials[i];
  sdata[tid] = a;
  __syncthreads();
  for (int d = 512; d > 0; d >>= 1) {
    if (tid < d) sdata[tid] += sdata[tid + d];
    __syncthreads();
  }
  if (tid == 0) *ldj_out = sdata[0];
}

extern "C" void kernel_launch(void* const* d_in, const int* in_sizes, int n_in,
                              void* d_out, int out_size, void* d_ws, size_t ws_size,
                              hipStream_t stream) {
  const float* x = (const float*)d_in[0];
  const int* eidx = (const int*)d_in[1];
  const float* W = (const float*)d_in[2];
  const float* B = (const float*)d_in[3];
  float* out = (float*)d_out;

  int n = in_sizes[0] / 128;
  int e = in_sizes[1] / 2;
  int m = e + n;
  const int* src = eidx;
  const int* dstv = eidx + e;

  size_t off = 0;
  auto alloc = [&](size_t bytes) {
    size_t r = off;
    off += (bytes + 255) & ~(size_t)255;
    return r;
  };
  char* ws = (char*)d_ws;
  int* cnt = (int*)(ws + alloc((size_t)n * 4));
  int* fill = (int*)(ws + alloc((size_t)n * 4));
  int* row_ptr = (int*)(ws + alloc((size_t)(n + 1) * 4));
  int* bsum = (int*)(ws + alloc((size_t)1024 * 4));
  float* dinv = (float*)(ws + alloc((size_t)n * 4));
  uint2* cw = (uint2*)(ws + alloc((size_t)m * 8));
  unsigned short* p = (unsigned short*)(ws + alloc((size_t)n * 64 * 2));    // bf16 A*x_in
  unsigned short* h1 = (unsigned short*)(ws + alloc((size_t)n * 128 * 2));  // bf16 hidden
  unsigned short* q = (unsigned short*)(ws + alloc((size_t)n * 128 * 2));   // bf16 A*h1
  unsigned short* xb = (unsigned short*)(ws + alloc((size_t)n * 128 * 2));  // bf16 state mirror
  unsigned short* wt0 = (unsigned short*)(ws + alloc((size_t)4 * 8192 * 2));
  unsigned short* wt1 = (unsigned short*)(ws + alloc((size_t)4 * 8192 * 2));
  float* b0c = (float*)(ws + alloc((size_t)4 * 128 * 4));
  float* b1c = (float*)(ws + alloc((size_t)4 * 128 * 4));
  int gblk = (n + 63) / 64;
  float* partials = (float*)(ws + alloc((size_t)4 * gblk * 4));

  int total = n * 128;
  int nb = (n + 1023) / 1024;
  init_out_kernel<<<(total + 255) / 256, 256, 0, stream>>>(x, out, xb, total);
  meta_init_kernel<<<(n + 255) / 256, 256, 0, stream>>>(cnt, fill, n);
  count_kernel<<<(e + 255) / 256, 256, 0, stream>>>(dstv, cnt, e);
  dinv_kernel<<<(n + 255) / 256, 256, 0, stream>>>(cnt, dinv, n);
  scan_blk_kernel<<<nb, 1024, 0, stream>>>(cnt, row_ptr, bsum, n);
  scan_top_kernel<<<1, 1024, 0, stream>>>(bsum, nb);
  scan_add_kernel<<<(n + 255) / 256, 256, 0, stream>>>(row_ptr, bsum, n, m);
  fill_kernel<<<(m + 255) / 256, 256, 0, stream>>>(src, dstv, dinv, row_ptr, fill, cw, e, n);
  prep_weights<<<256, 256, 0, stream>>>(W, B, wt0, wt1, b0c, b1c);

  const int hs_xin[4] = {0, 64, 0, 64};
  int pgrid = (n * 64 + 255) / 256;  // one wave per node
  for (int hsi = 0; hsi < 4; ++hsi) {
    int xin = hs_xin[hsi];
    int xout = 64 - xin;
    // p = A * x_in (64 feats from bf16 mirror)
    propagate_kernel<16><<<pgrid, 256, 0, stream>>>(
        (const unsigned int*)xb, 64, xin / 2, (unsigned int*)p, 32, row_ptr, cw, n);
    gemm_layer0<<<gblk, 256, 0, stream>>>(p, wt0 + (size_t)hsi * 8192, b0c + hsi * 128, h1, n);
    // q = A * h1 (128 feats)
    propagate_kernel<32><<<pgrid, 256, 0, stream>>>(
        (const unsigned int*)h1, 64, 0, (unsigned int*)q, 64, row_ptr, cw, n);
    gemm_final<<<gblk, 256, 0, stream>>>(q, wt1 + (size_t)hsi * 8192, b1c + hsi * 128, out, xb,
                                         xout, partials + (size_t)hsi * gblk, n);
  }
  ldj_reduce_kernel<<<1, 1024, 0, stream>>>(partials, 4 * gblk, out + total);
}

// Round 7
// 454.614 us; speedup vs baseline: 1.3547x; 1.0572x over previous
//
#include <hip/hip_runtime.h>
#include <math.h>

// Graph normalizing flow on MI355X.
// State x (N x 128) fp32 lives in d_out; bf16 mirror xb for propagation gathers.
// ldj at d_out[N*128]. CSR-by-destination gather (packed col+weight uint2).
// A(hW)=(Ah)W rewrite: s/t GCN layer-0 share one 64-feat propagation.
// Dense layers: bf16 MFMA GEMMs, LDS-staged epilogues -> coalesced float4/uint4 I/O.
// ldj: per-block non-atomic partials + one deterministic reduce kernel.
// CSR build: rank captured in count pass -> fill is atomic-free.
// Propagate: one wave/node, predicated constant-unroll gather loop (max MLP).

typedef __attribute__((ext_vector_type(8))) short bf16x8;
typedef __attribute__((ext_vector_type(4))) float f32x4;

__device__ __forceinline__ float bf_lo(unsigned int u) { return __uint_as_float(u << 16); }
__device__ __forceinline__ float bf_hi(unsigned int u) { return __uint_as_float(u & 0xffff0000u); }
__device__ __forceinline__ unsigned short f2bf(float f) {
  unsigned int u = __float_as_uint(f);
  u = (u + 0x7fffu + ((u >> 16) & 1u)) >> 16;  // round-to-nearest-even
  return (unsigned short)u;
}
__device__ __forceinline__ unsigned int pack2(float a, float b) {
  return (unsigned int)f2bf(a) | ((unsigned int)f2bf(b) << 16);
}

__global__ void init_out_kernel(const float4* __restrict__ x4, float4* __restrict__ out4,
                                uint2* __restrict__ xb2, int total4) {
  int i = blockIdx.x * blockDim.x + threadIdx.x;
  if (i < total4) {
    float4 v = x4[i];
    out4[i] = v;
    xb2[i] = make_uint2(pack2(v.x, v.y), pack2(v.z, v.w));
  }
}

// cnt must be zeroed (hipMemsetAsync). rank[i] = arrival order of edge i at its dst.
__global__ void count_rank_kernel(const int* __restrict__ dst, int* __restrict__ cnt,
                                  unsigned short* __restrict__ rank, int e) {
  int i = blockIdx.x * blockDim.x + threadIdx.x;
  if (i < e) rank[i] = (unsigned short)atomicAdd(&cnt[dst[i]], 1);
}

// --- parallel exclusive scan over (cnt[i]+1) [self-loop]; also emits dinv ---
__global__ void scan_blk_kernel(const int* __restrict__ cnt, int* __restrict__ row_ptr,
                                int* __restrict__ bsum, float* __restrict__ dinv, int n) {
  __shared__ int sdata[1024];
  int tid = threadIdx.x;
  int i = blockIdx.x * 1024 + tid;
  int v = (i < n) ? (cnt[i] + 1) : 0;
  if (i < n) dinv[i] = rsqrtf((float)v);
  sdata[tid] = v;
  __syncthreads();
  for (int d = 1; d < 1024; d <<= 1) {
    int t = (tid >= d) ? sdata[tid - d] : 0;
    __syncthreads();
    sdata[tid] += t;
    __syncthreads();
  }
  if (i < n) row_ptr[i] = sdata[tid] - v;  // exclusive within block
  if (tid == 1023) bsum[blockIdx.x] = sdata[1023];
}

__global__ void scan_top_kernel(int* __restrict__ bsum, int nb) {
  __shared__ int sdata[1024];
  int tid = threadIdx.x;
  int v = (tid < nb) ? bsum[tid] : 0;
  sdata[tid] = v;
  __syncthreads();
  for (int d = 1; d < 1024; d <<= 1) {
    int t = (tid >= d) ? sdata[tid - d] : 0;
    __syncthreads();
    sdata[tid] += t;
    __syncthreads();
  }
  if (tid < nb) bsum[tid] = sdata[tid] - v;  // exclusive block offsets
}

__global__ void scan_add_kernel(int* __restrict__ row_ptr, const int* __restrict__ bsum,
                                int n, int m) {
  int i = blockIdx.x * blockDim.x + threadIdx.x;
  if (i < n) row_ptr[i] += bsum[i >> 10];
  if (i == 0) row_ptr[n] = m;
}

// Atomic-free fill: edges land at row_ptr[d]+rank[i]; self-loop at last slot (cnt[v]).
__global__ void fill_kernel(const int* __restrict__ src, const int* __restrict__ dst,
                            const unsigned short* __restrict__ rank,
                            const float* __restrict__ dinv, const int* __restrict__ row_ptr,
                            const int* __restrict__ cnt, uint2* __restrict__ cw, int e, int n) {
  int i = blockIdx.x * blockDim.x + threadIdx.x;
  if (i < e) {
    int s = src[i], d = dst[i];
    int pos = row_ptr[d] + (int)rank[i];
    cw[pos] = make_uint2((unsigned)s, __float_as_uint(dinv[s] * dinv[d]));
  } else if (i < e + n) {
    int v = i - e;
    int pos = row_ptr[v] + cnt[v];
    float dv = dinv[v];
    cw[pos] = make_uint2((unsigned)v, __float_as_uint(dv * dv));
  }
}

// Build bf16 transposed weight mats + fp32 bias vectors for all 4 half-steps.
__global__ void prep_weights(const float* __restrict__ W, const float* __restrict__ B,
                             unsigned short* __restrict__ WT0, unsigned short* __restrict__ WT1,
                             float* __restrict__ b0c, float* __restrict__ b1c) {
  int idx = blockIdx.x * blockDim.x + threadIdx.x;
  if (idx < 65536) {
    int hsi = idx >> 14;
    int lay = (idx >> 13) & 1;
    int j = (idx >> 6) & 127;
    int k = idx & 63;
    int i = hsi >> 1, half = hsi & 1;
    int g = half * 4 + (j < 64 ? 0 : 2) + i;
    float v = W[(((size_t)g * 2 + lay) * 64 + k) * 64 + (j & 63)];
    unsigned short* dst = lay ? WT1 : WT0;
    dst[(size_t)hsi * 8192 + j * 64 + k] = f2bf(v);
  }
  if (idx < 1024) {
    int hsi = idx >> 8;
    int lay = (idx >> 7) & 1;
    int j = idx & 127;
    int i = hsi >> 1, half = hsi & 1;
    int g = half * 4 + (j < 64 ? 0 : 2) + i;
    (lay ? b1c : b0c)[hsi * 128 + j] = B[(g * 2 + lay) * 64 + (j & 63)];
  }
}

// One wave per node. UPN = uint2-chunks per row (16 -> 64 feats, 32 -> 128 feats).
// Lanes: eo = edge slot (64/UPN), li = uint2 index. Predicated constant unroll:
// every iteration issues UNR independent cw loads + UNR gathers (invalid -> w=0,
// clamped index; duplicate loads are cache hits). No serial remainder loop.
template <int UPN, int UNR>
__global__ void propagate_kernel(const unsigned int* __restrict__ X, int ldu, int xoffu,
                                 unsigned int* __restrict__ Y, int ldyu,
                                 const int* __restrict__ row_ptr, const uint2* __restrict__ cw,
                                 int n) {
  constexpr int EPG = 64 / UPN;  // edge slots per wave
  int wid0 = (blockIdx.x * blockDim.x + threadIdx.x) >> 6;
  if (wid0 >= n) return;
  int wid = __builtin_amdgcn_readfirstlane(wid0);  // wave-uniform -> scalar loads
  int lane = threadIdx.x & 63;
  int eo = lane / UPN;
  int li = lane % UPN;
  int beg = row_ptr[wid], end = row_ptr[wid + 1];
  float a0 = 0.f, a1 = 0.f, a2 = 0.f, a3 = 0.f;
  for (int i = beg + eo; i < end; i += UNR * EPG) {
    uint2 ee[UNR];
    uint2 uu[UNR];
    float ww[UNR];
#pragma unroll
    for (int k = 0; k < UNR; ++k) {
      int idx = i + k * EPG;
      ee[k] = cw[idx < end ? idx : end - 1];
    }
#pragma unroll
    for (int k = 0; k < UNR; ++k) {
      int idx = i + k * EPG;
      ww[k] = (idx < end) ? __uint_as_float(ee[k].y) : 0.f;
      uu[k] = *((const uint2*)(X + (size_t)ee[k].x * ldu + xoffu) + li);
    }
#pragma unroll
    for (int k = 0; k < UNR; ++k) {
      a0 += ww[k] * bf_lo(uu[k].x);
      a1 += ww[k] * bf_hi(uu[k].x);
      a2 += ww[k] * bf_lo(uu[k].y);
      a3 += ww[k] * bf_hi(uu[k].y);
    }
  }
#pragma unroll
  for (int ms = UPN; ms < 64; ms <<= 1) {
    a0 += __shfl_xor(a0, ms);
    a1 += __shfl_xor(a1, ms);
    a2 += __shfl_xor(a2, ms);
    a3 += __shfl_xor(a3, ms);
  }
  if (lane < UPN) {
    uint2 r;
    r.x = pack2(a0, a1);
    r.y = pack2(a2, a3);
    *((uint2*)(Y + (size_t)wid * ldyu) + li) = r;
  }
}

// h1[r][j] = bf16(relu(p[r] @ Wcat0 + b0cat)). Phase1: MFMA -> LDS (bf16 tile).
// Phase2: coalesced uint4 write-out of 64x128 bf16 tile.
__global__ __launch_bounds__(256) void gemm_layer0(const unsigned short* __restrict__ P,
                                                   const unsigned short* __restrict__ WT,
                                                   const float* __restrict__ bc,
                                                   unsigned short* __restrict__ H1, int n) {
  __shared__ unsigned short cs[64][136];
  int w = threadIdx.x >> 6, l = threadIdx.x & 63;
  int rbase0 = blockIdx.x * 64;
  int lr = l & 15, kg = l >> 4;
  int arow = rbase0 + w * 16 + lr;
  if (arow >= n) arow = n - 1;  // clamp; result discarded by guarded store
  const bf16x8* ap = (const bf16x8*)(P + (size_t)arow * 64);
  bf16x8 a0 = ap[kg];
  bf16x8 a1 = ap[kg + 4];
  f32x4 acc[8];
#pragma unroll
  for (int ct = 0; ct < 8; ++ct) {
    const bf16x8* bp = (const bf16x8*)(WT + (size_t)(ct * 16 + lr) * 64);
    f32x4 c = {0.f, 0.f, 0.f, 0.f};
    c = __builtin_amdgcn_mfma_f32_16x16x32_bf16(a0, bp[kg], c, 0, 0, 0);
    c = __builtin_amdgcn_mfma_f32_16x16x32_bf16(a1, bp[kg + 4], c, 0, 0, 0);
    acc[ct] = c;
  }
#pragma unroll
  for (int ct = 0; ct < 8; ++ct) {
    int colj = ct * 16 + lr;
    float bb = bc[colj];
#pragma unroll
    for (int i2 = 0; i2 < 4; ++i2) {
      int lrow = w * 16 + kg * 4 + i2;  // C/D: col=lane&15, row=(lane>>4)*4+reg
      cs[lrow][colj] = f2bf(fmaxf(acc[ct][i2] + bb, 0.f));
    }
  }
  __syncthreads();
  int row = threadIdx.x >> 2;
  int cbase = (threadIdx.x & 3) * 32;
  if (rbase0 + row < n) {
    uint4* dstp = (uint4*)(H1 + (size_t)(rbase0 + row) * 128 + cbase);
#pragma unroll
    for (int ci = 0; ci < 4; ++ci) dstp[ci] = *(const uint4*)(&cs[row][cbase + ci * 8]);
  }
}

// s=sigmoid(q[:,:64]@Ws1+bs), t=sigmoid(q[:,64:]@Wt1+bt).
// Phase1: MFMA + sigmoid -> LDS exp(s), t tiles; per-block ldj partial (NO atomics).
// Phase2: coalesced float4 RMW of Xout half + uint2 bf16-mirror stores.
__global__ __launch_bounds__(256) void gemm_final(const unsigned short* __restrict__ Q,
                                                  const unsigned short* __restrict__ WT,
                                                  const float* __restrict__ bc,
                                                  float* __restrict__ Xout,
                                                  unsigned short* __restrict__ Xb, int xoff,
                                                  float* __restrict__ partials, int n) {
  __shared__ float es[64][68];
  __shared__ float tv[64][68];
  __shared__ float redbuf[4];
  int w = threadIdx.x >> 6, l = threadIdx.x & 63;
  int rbase0 = blockIdx.x * 64;
  int lr = l & 15, kg = l >> 4;
  int arow = rbase0 + w * 16 + lr;
  if (arow >= n) arow = n - 1;
  const bf16x8* ap = (const bf16x8*)(Q + (size_t)arow * 128);
  bf16x8 as0 = ap[kg], as1 = ap[kg + 4];
  bf16x8 at0 = ap[kg + 8], at1 = ap[kg + 12];
  f32x4 acc[8];
#pragma unroll
  for (int ct = 0; ct < 8; ++ct) {
    const bf16x8* bp = (const bf16x8*)(WT + (size_t)(ct * 16 + lr) * 64);
    f32x4 c = {0.f, 0.f, 0.f, 0.f};
    bf16x8 x0 = (ct < 4) ? as0 : at0;
    bf16x8 x1 = (ct < 4) ? as1 : at1;
    c = __builtin_amdgcn_mfma_f32_16x16x32_bf16(x0, bp[kg], c, 0, 0, 0);
    c = __builtin_amdgcn_mfma_f32_16x16x32_bf16(x1, bp[kg + 4], c, 0, 0, 0);
    acc[ct] = c;
  }
  float wldj = 0.f;
#pragma unroll
  for (int ct = 0; ct < 4; ++ct) {
    int colj = ct * 16 + lr;
    float bs = bc[colj], bt = bc[colj + 64];
#pragma unroll
    for (int i2 = 0; i2 < 4; ++i2) {
      int lrow = w * 16 + kg * 4 + i2;
      float sv = 1.f / (1.f + __expf(-(acc[ct][i2] + bs)));
      float tvv = 1.f / (1.f + __expf(-(acc[ct + 4][i2] + bt)));
      es[lrow][colj] = __expf(sv);
      tv[lrow][colj] = tvv;
      if (rbase0 + lrow < n) wldj += sv;
    }
  }
#pragma unroll
  for (int off2 = 32; off2 > 0; off2 >>= 1) wldj += __shfl_down(wldj, off2);
  if (l == 0) redbuf[w] = wldj;
  __syncthreads();
  if (threadIdx.x == 0)
    partials[blockIdx.x] = redbuf[0] + redbuf[1] + redbuf[2] + redbuf[3];
  int row = threadIdx.x >> 2;
  int c0 = (threadIdx.x & 3) * 16;
  int grow = rbase0 + row;
  if (grow < n) {
    size_t base = (size_t)grow * 128 + xoff;
#pragma unroll
    for (int ci = 0; ci < 4; ++ci) {
      int c = c0 + ci * 4;
      float4 xv = *(const float4*)(Xout + base + c);
      float4 nv;
      nv.x = xv.x * es[row][c + 0] + tv[row][c + 0];
      nv.y = xv.y * es[row][c + 1] + tv[row][c + 1];
      nv.z = xv.z * es[row][c + 2] + tv[row][c + 2];
      nv.w = xv.w * es[row][c + 3] + tv[row][c + 3];
      *(float4*)(Xout + base + c) = nv;
      uint2 bb;
      bb.x = pack2(nv.x, nv.y);
      bb.y = pack2(nv.z, nv.w);
      *(uint2*)(Xb + base + c) = bb;
    }
  }
}

// Deterministic single-block sum of np partials -> *ldj_out (overwrite).
__global__ void ldj_reduce_kernel(const float* __restrict__ partials, int np,
                                  float* __restrict__ ldj_out) {
  __shared__ float sdata[1024];
  int tid = threadIdx.x;
  float a = 0.f;
  for (int i = tid; i < np; i += 1024) a += partials[i];
  sdata[tid] = a;
  __syncthreads();
  for (int d = 512; d > 0; d >>= 1) {
    if (tid < d) sdata[tid] += sdata[tid + d];
    __syncthreads();
  }
  if (tid == 0) *ldj_out = sdata[0];
}

extern "C" void kernel_launch(void* const* d_in, const int* in_sizes, int n_in,
                              void* d_out, int out_size, void* d_ws, size_t ws_size,
                              hipStream_t stream) {
  const float* x = (const float*)d_in[0];
  const int* eidx = (const int*)d_in[1];
  const float* W = (const float*)d_in[2];
  const float* B = (const float*)d_in[3];
  float* out = (float*)d_out;

  int n = in_sizes[0] / 128;
  int e = in_sizes[1] / 2;
  int m = e + n;
  const int* src = eidx;
  const int* dstv = eidx + e;

  size_t off = 0;
  auto alloc = [&](size_t bytes) {
    size_t r = off;
    off += (bytes + 255) & ~(size_t)255;
    return r;
  };
  char* ws = (char*)d_ws;
  int* cnt = (int*)(ws + alloc((size_t)n * 4));
  unsigned short* rank = (unsigned short*)(ws + alloc((size_t)e * 2));
  int* row_ptr = (int*)(ws + alloc((size_t)(n + 1) * 4));
  int* bsum = (int*)(ws + alloc((size_t)1024 * 4));
  float* dinv = (float*)(ws + alloc((size_t)n * 4));
  uint2* cw = (uint2*)(ws + alloc((size_t)m * 8));
  unsigned short* p = (unsigned short*)(ws + alloc((size_t)n * 64 * 2));    // bf16 A*x_in
  unsigned short* h1 = (unsigned short*)(ws + alloc((size_t)n * 128 * 2));  // bf16 hidden
  unsigned short* q = (unsigned short*)(ws + alloc((size_t)n * 128 * 2));   // bf16 A*h1
  unsigned short* xb = (unsigned short*)(ws + alloc((size_t)n * 128 * 2));  // bf16 state mirror
  unsigned short* wt0 = (unsigned short*)(ws + alloc((size_t)4 * 8192 * 2));
  unsigned short* wt1 = (unsigned short*)(ws + alloc((size_t)4 * 8192 * 2));
  float* b0c = (float*)(ws + alloc((size_t)4 * 128 * 4));
  float* b1c = (float*)(ws + alloc((size_t)4 * 128 * 4));
  int gblk = (n + 63) / 64;
  float* partials = (float*)(ws + alloc((size_t)4 * gblk * 4));

  int total4 = n * 32;  // float4 elements of state
  int nb = (n + 1023) / 1024;
  hipMemsetAsync(cnt, 0, (size_t)n * 4, stream);
  init_out_kernel<<<(total4 + 255) / 256, 256, 0, stream>>>((const float4*)x, (float4*)out,
                                                            (uint2*)xb, total4);
  count_rank_kernel<<<(e + 255) / 256, 256, 0, stream>>>(dstv, cnt, rank, e);
  scan_blk_kernel<<<nb, 1024, 0, stream>>>(cnt, row_ptr, bsum, dinv, n);
  scan_top_kernel<<<1, 1024, 0, stream>>>(bsum, nb);
  scan_add_kernel<<<(n + 255) / 256, 256, 0, stream>>>(row_ptr, bsum, n, m);
  fill_kernel<<<(m + 255) / 256, 256, 0, stream>>>(src, dstv, rank, dinv, row_ptr, cnt, cw, e, n);
  prep_weights<<<256, 256, 0, stream>>>(W, B, wt0, wt1, b0c, b1c);

  const int hs_xin[4] = {0, 64, 0, 64};
  int pgrid = (n * 64 + 255) / 256;  // one wave per node
  for (int hsi = 0; hsi < 4; ++hsi) {
    int xin = hs_xin[hsi];
    int xout = 64 - xin;
    // p = A * x_in (64 feats from bf16 mirror); 4 slots x 4 unroll = 16 edges/iter
    propagate_kernel<16, 4><<<pgrid, 256, 0, stream>>>(
        (const unsigned int*)xb, 64, xin / 2, (unsigned int*)p, 32, row_ptr, cw, n);
    gemm_layer0<<<gblk, 256, 0, stream>>>(p, wt0 + (size_t)hsi * 8192, b0c + hsi * 128, h1, n);
    // q = A * h1 (128 feats); 2 slots x 8 unroll = 16 edges/iter
    propagate_kernel<32, 8><<<pgrid, 256, 0, stream>>>(
        (const unsigned int*)h1, 64, 0, (unsigned int*)q, 64, row_ptr, cw, n);
    gemm_final<<<gblk, 256, 0, stream>>>(q, wt1 + (size_t)hsi * 8192, b1c + hsi * 128, out, xb,
                                         xout, partials + (size_t)hsi * gblk, n);
  }
  ldj_reduce_kernel<<<1, 1024, 0, stream>>>(partials, 4 * gblk, out + total4 * 4);
}

// Round 8
// 401.437 us; speedup vs baseline: 1.5341x; 1.1325x over previous
//
#include <hip/hip_runtime.h>
#include <math.h>

// Graph normalizing flow on MI355X.
// State x (N x 128) fp32 lives in d_out; bf16 mirror xb for propagation gathers.
// ldj at d_out[N*128]. CSR-by-destination gather (packed col+weight uint2).
// A(hW)=(Ah)W rewrite: s/t GCN layer-0 share one 64-feat propagation.
// Dense layers: bf16 MFMA GEMMs, LDS-staged epilogues -> coalesced float4/uint4 I/O.
// ldj: per-block non-atomic partials + one deterministic reduce kernel.
// CSR build: rank captured in count pass -> fill is atomic-free.
// Propagate: one wave/node, uint4 (16B/lane) predicated constant-unroll gathers,
// __launch_bounds__(256,1) so the allocator keeps all UNR loads in flight.

typedef __attribute__((ext_vector_type(8))) short bf16x8;
typedef __attribute__((ext_vector_type(4))) float f32x4;

__device__ __forceinline__ float bf_lo(unsigned int u) { return __uint_as_float(u << 16); }
__device__ __forceinline__ float bf_hi(unsigned int u) { return __uint_as_float(u & 0xffff0000u); }
__device__ __forceinline__ unsigned short f2bf(float f) {
  unsigned int u = __float_as_uint(f);
  u = (u + 0x7fffu + ((u >> 16) & 1u)) >> 16;  // round-to-nearest-even
  return (unsigned short)u;
}
__device__ __forceinline__ unsigned int pack2(float a, float b) {
  return (unsigned int)f2bf(a) | ((unsigned int)f2bf(b) << 16);
}

__global__ void init_out_kernel(const float4* __restrict__ x4, float4* __restrict__ out4,
                                uint2* __restrict__ xb2, int total4) {
  int i = blockIdx.x * blockDim.x + threadIdx.x;
  if (i < total4) {
    float4 v = x4[i];
    out4[i] = v;
    xb2[i] = make_uint2(pack2(v.x, v.y), pack2(v.z, v.w));
  }
}

// cnt must be zeroed (hipMemsetAsync). rank[i] = arrival order of edge i at its dst.
__global__ void count_rank_kernel(const int* __restrict__ dst, int* __restrict__ cnt,
                                  unsigned short* __restrict__ rank, int e) {
  int i = blockIdx.x * blockDim.x + threadIdx.x;
  if (i < e) rank[i] = (unsigned short)atomicAdd(&cnt[dst[i]], 1);
}

// --- parallel exclusive scan over (cnt[i]+1) [self-loop]; also emits dinv ---
__global__ void scan_blk_kernel(const int* __restrict__ cnt, int* __restrict__ row_ptr,
                                int* __restrict__ bsum, float* __restrict__ dinv, int n) {
  __shared__ int sdata[1024];
  int tid = threadIdx.x;
  int i = blockIdx.x * 1024 + tid;
  int v = (i < n) ? (cnt[i] + 1) : 0;
  if (i < n) dinv[i] = rsqrtf((float)v);
  sdata[tid] = v;
  __syncthreads();
  for (int d = 1; d < 1024; d <<= 1) {
    int t = (tid >= d) ? sdata[tid - d] : 0;
    __syncthreads();
    sdata[tid] += t;
    __syncthreads();
  }
  if (i < n) row_ptr[i] = sdata[tid] - v;  // exclusive within block
  if (tid == 1023) bsum[blockIdx.x] = sdata[1023];
}

__global__ void scan_top_kernel(int* __restrict__ bsum, int nb) {
  __shared__ int sdata[1024];
  int tid = threadIdx.x;
  int v = (tid < nb) ? bsum[tid] : 0;
  sdata[tid] = v;
  __syncthreads();
  for (int d = 1; d < 1024; d <<= 1) {
    int t = (tid >= d) ? sdata[tid - d] : 0;
    __syncthreads();
    sdata[tid] += t;
    __syncthreads();
  }
  if (tid < nb) bsum[tid] = sdata[tid] - v;  // exclusive block offsets
}

__global__ void scan_add_kernel(int* __restrict__ row_ptr, const int* __restrict__ bsum,
                                int n, int m) {
  int i = blockIdx.x * blockDim.x + threadIdx.x;
  if (i < n) row_ptr[i] += bsum[i >> 10];
  if (i == 0) row_ptr[n] = m;
}

// Atomic-free fill: edges land at row_ptr[d]+rank[i]; self-loop at last slot (cnt[v]).
__global__ void fill_kernel(const int* __restrict__ src, const int* __restrict__ dst,
                            const unsigned short* __restrict__ rank,
                            const float* __restrict__ dinv, const int* __restrict__ row_ptr,
                            const int* __restrict__ cnt, uint2* __restrict__ cw, int e, int n) {
  int i = blockIdx.x * blockDim.x + threadIdx.x;
  if (i < e) {
    int s = src[i], d = dst[i];
    int pos = row_ptr[d] + (int)rank[i];
    cw[pos] = make_uint2((unsigned)s, __float_as_uint(dinv[s] * dinv[d]));
  } else if (i < e + n) {
    int v = i - e;
    int pos = row_ptr[v] + cnt[v];
    float dv = dinv[v];
    cw[pos] = make_uint2((unsigned)v, __float_as_uint(dv * dv));
  }
}

// Build bf16 transposed weight mats + fp32 bias vectors for all 4 half-steps.
__global__ void prep_weights(const float* __restrict__ W, const float* __restrict__ B,
                             unsigned short* __restrict__ WT0, unsigned short* __restrict__ WT1,
                             float* __restrict__ b0c, float* __restrict__ b1c) {
  int idx = blockIdx.x * blockDim.x + threadIdx.x;
  if (idx < 65536) {
    int hsi = idx >> 14;
    int lay = (idx >> 13) & 1;
    int j = (idx >> 6) & 127;
    int k = idx & 63;
    int i = hsi >> 1, half = hsi & 1;
    int g = half * 4 + (j < 64 ? 0 : 2) + i;
    float v = W[(((size_t)g * 2 + lay) * 64 + k) * 64 + (j & 63)];
    unsigned short* dst = lay ? WT1 : WT0;
    dst[(size_t)hsi * 8192 + j * 64 + k] = f2bf(v);
  }
  if (idx < 1024) {
    int hsi = idx >> 8;
    int lay = (idx >> 7) & 1;
    int j = idx & 127;
    int i = hsi >> 1, half = hsi & 1;
    int g = half * 4 + (j < 64 ? 0 : 2) + i;
    (lay ? b1c : b0c)[hsi * 128 + j] = B[(g * 2 + lay) * 64 + (j & 63)];
  }
}

// One wave per node. LPR = lanes per row (uint4 units: 8 -> 64 feats, 16 -> 128).
// EPG = 64/LPR edge slots. Predicated constant unroll: every iteration issues
// UNR independent cw loads + UNR uint4 gathers (invalid -> clamped idx, w=0).
template <int LPR, int UNR>
__global__ __launch_bounds__(256, 1) void propagate_kernel(
    const uint4* __restrict__ X, int ldu4, int xoff4, uint4* __restrict__ Y, int ldy4,
    const int* __restrict__ row_ptr, const uint2* __restrict__ cw, int n) {
  constexpr int EPG = 64 / LPR;  // edge slots per wave
  int wid0 = (blockIdx.x * blockDim.x + threadIdx.x) >> 6;
  if (wid0 >= n) return;
  int wid = __builtin_amdgcn_readfirstlane(wid0);  // wave-uniform -> scalar loads
  int lane = threadIdx.x & 63;
  int eo = lane / LPR;
  int li = lane % LPR;
  int beg = row_ptr[wid], end = row_ptr[wid + 1];
  float a0 = 0.f, a1 = 0.f, a2 = 0.f, a3 = 0.f, a4 = 0.f, a5 = 0.f, a6 = 0.f, a7 = 0.f;
  for (int i = beg + eo; i < end; i += UNR * EPG) {
    uint2 ee[UNR];
    uint4 uu[UNR];
    float ww[UNR];
#pragma unroll
    for (int k = 0; k < UNR; ++k) {
      int idx = i + k * EPG;
      ee[k] = cw[idx < end ? idx : end - 1];
    }
#pragma unroll
    for (int k = 0; k < UNR; ++k) {
      int idx = i + k * EPG;
      ww[k] = (idx < end) ? __uint_as_float(ee[k].y) : 0.f;
      uu[k] = X[(size_t)ee[k].x * ldu4 + xoff4 + li];
    }
#pragma unroll
    for (int k = 0; k < UNR; ++k) {
      a0 += ww[k] * bf_lo(uu[k].x); a1 += ww[k] * bf_hi(uu[k].x);
      a2 += ww[k] * bf_lo(uu[k].y); a3 += ww[k] * bf_hi(uu[k].y);
      a4 += ww[k] * bf_lo(uu[k].z); a5 += ww[k] * bf_hi(uu[k].z);
      a6 += ww[k] * bf_lo(uu[k].w); a7 += ww[k] * bf_hi(uu[k].w);
    }
  }
#pragma unroll
  for (int ms = LPR; ms < 64; ms <<= 1) {
    a0 += __shfl_xor(a0, ms); a1 += __shfl_xor(a1, ms);
    a2 += __shfl_xor(a2, ms); a3 += __shfl_xor(a3, ms);
    a4 += __shfl_xor(a4, ms); a5 += __shfl_xor(a5, ms);
    a6 += __shfl_xor(a6, ms); a7 += __shfl_xor(a7, ms);
  }
  if (lane < LPR) {
    uint4 r;
    r.x = pack2(a0, a1);
    r.y = pack2(a2, a3);
    r.z = pack2(a4, a5);
    r.w = pack2(a6, a7);
    Y[(size_t)wid * ldy4 + li] = r;
  }
}

// h1[r][j] = bf16(relu(p[r] @ Wcat0 + b0cat)). Phase1: MFMA -> LDS (bf16 tile).
// Phase2: coalesced uint4 write-out of 64x128 bf16 tile.
__global__ __launch_bounds__(256) void gemm_layer0(const unsigned short* __restrict__ P,
                                                   const unsigned short* __restrict__ WT,
                                                   const float* __restrict__ bc,
                                                   unsigned short* __restrict__ H1, int n) {
  __shared__ unsigned short cs[64][136];
  int w = threadIdx.x >> 6, l = threadIdx.x & 63;
  int rbase0 = blockIdx.x * 64;
  int lr = l & 15, kg = l >> 4;
  int arow = rbase0 + w * 16 + lr;
  if (arow >= n) arow = n - 1;  // clamp; result discarded by guarded store
  const bf16x8* ap = (const bf16x8*)(P + (size_t)arow * 64);
  bf16x8 a0 = ap[kg];
  bf16x8 a1 = ap[kg + 4];
  f32x4 acc[8];
#pragma unroll
  for (int ct = 0; ct < 8; ++ct) {
    const bf16x8* bp = (const bf16x8*)(WT + (size_t)(ct * 16 + lr) * 64);
    f32x4 c = {0.f, 0.f, 0.f, 0.f};
    c = __builtin_amdgcn_mfma_f32_16x16x32_bf16(a0, bp[kg], c, 0, 0, 0);
    c = __builtin_amdgcn_mfma_f32_16x16x32_bf16(a1, bp[kg + 4], c, 0, 0, 0);
    acc[ct] = c;
  }
#pragma unroll
  for (int ct = 0; ct < 8; ++ct) {
    int colj = ct * 16 + lr;
    float bb = bc[colj];
#pragma unroll
    for (int i2 = 0; i2 < 4; ++i2) {
      int lrow = w * 16 + kg * 4 + i2;  // C/D: col=lane&15, row=(lane>>4)*4+reg
      cs[lrow][colj] = f2bf(fmaxf(acc[ct][i2] + bb, 0.f));
    }
  }
  __syncthreads();
  int row = threadIdx.x >> 2;
  int cbase = (threadIdx.x & 3) * 32;
  if (rbase0 + row < n) {
    uint4* dstp = (uint4*)(H1 + (size_t)(rbase0 + row) * 128 + cbase);
#pragma unroll
    for (int ci = 0; ci < 4; ++ci) dstp[ci] = *(const uint4*)(&cs[row][cbase + ci * 8]);
  }
}

// s=sigmoid(q[:,:64]@Ws1+bs), t=sigmoid(q[:,64:]@Wt1+bt).
// Phase1: MFMA + sigmoid -> LDS exp(s), t tiles; per-block ldj partial (NO atomics).
// Phase2: coalesced float4 RMW of Xout half + uint2 bf16-mirror stores.
__global__ __launch_bounds__(256) void gemm_final(const unsigned short* __restrict__ Q,
                                                  const unsigned short* __restrict__ WT,
                                                  const float* __restrict__ bc,
                                                  float* __restrict__ Xout,
                                                  unsigned short* __restrict__ Xb, int xoff,
                                                  float* __restrict__ partials, int n) {
  __shared__ float es[64][68];
  __shared__ float tv[64][68];
  __shared__ float redbuf[4];
  int w = threadIdx.x >> 6, l = threadIdx.x & 63;
  int rbase0 = blockIdx.x * 64;
  int lr = l & 15, kg = l >> 4;
  int arow = rbase0 + w * 16 + lr;
  if (arow >= n) arow = n - 1;
  const bf16x8* ap = (const bf16x8*)(Q + (size_t)arow * 128);
  bf16x8 as0 = ap[kg], as1 = ap[kg + 4];
  bf16x8 at0 = ap[kg + 8], at1 = ap[kg + 12];
  f32x4 acc[8];
#pragma unroll
  for (int ct = 0; ct < 8; ++ct) {
    const bf16x8* bp = (const bf16x8*)(WT + (size_t)(ct * 16 + lr) * 64);
    f32x4 c = {0.f, 0.f, 0.f, 0.f};
    bf16x8 x0 = (ct < 4) ? as0 : at0;
    bf16x8 x1 = (ct < 4) ? as1 : at1;
    c = __builtin_amdgcn_mfma_f32_16x16x32_bf16(x0, bp[kg], c, 0, 0, 0);
    c = __builtin_amdgcn_mfma_f32_16x16x32_bf16(x1, bp[kg + 4], c, 0, 0, 0);
    acc[ct] = c;
  }
  float wldj = 0.f;
#pragma unroll
  for (int ct = 0; ct < 4; ++ct) {
    int colj = ct * 16 + lr;
    float bs = bc[colj], bt = bc[colj + 64];
#pragma unroll
    for (int i2 = 0; i2 < 4; ++i2) {
      int lrow = w * 16 + kg * 4 + i2;
      float sv = 1.f / (1.f + __expf(-(acc[ct][i2] + bs)));
      float tvv = 1.f / (1.f + __expf(-(acc[ct + 4][i2] + bt)));
      es[lrow][colj] = __expf(sv);
      tv[lrow][colj] = tvv;
      if (rbase0 + lrow < n) wldj += sv;
    }
  }
#pragma unroll
  for (int off2 = 32; off2 > 0; off2 >>= 1) wldj += __shfl_down(wldj, off2);
  if (l == 0) redbuf[w] = wldj;
  __syncthreads();
  if (threadIdx.x == 0)
    partials[blockIdx.x] = redbuf[0] + redbuf[1] + redbuf[2] + redbuf[3];
  int row = threadIdx.x >> 2;
  int c0 = (threadIdx.x & 3) * 16;
  int grow = rbase0 + row;
  if (grow < n) {
    size_t base = (size_t)grow * 128 + xoff;
#pragma unroll
    for (int ci = 0; ci < 4; ++ci) {
      int c = c0 + ci * 4;
      float4 xv = *(const float4*)(Xout + base + c);
      float4 nv;
      nv.x = xv.x * es[row][c + 0] + tv[row][c + 0];
      nv.y = xv.y * es[row][c + 1] + tv[row][c + 1];
      nv.z = xv.z * es[row][c + 2] + tv[row][c + 2];
      nv.w = xv.w * es[row][c + 3] + tv[row][c + 3];
      *(float4*)(Xout + base + c) = nv;
      uint2 bb;
      bb.x = pack2(nv.x, nv.y);
      bb.y = pack2(nv.z, nv.w);
      *(uint2*)(Xb + base + c) = bb;
    }
  }
}

// Deterministic single-block sum of np partials -> *ldj_out (overwrite).
__global__ void ldj_reduce_kernel(const float* __restrict__ partials, int np,
                                  float* __restrict__ ldj_out) {
  __shared__ float sdata[1024];
  int tid = threadIdx.x;
  float a = 0.f;
  for (int i = tid; i < np; i += 1024) a += partials[i];
  sdata[tid] = a;
  __syncthreads();
  for (int d = 512; d > 0; d >>= 1) {
    if (tid < d) sdata[tid] += sdata[tid + d];
    __syncthreads();
  }
  if (tid == 0) *ldj_out = sdata[0];
}

extern "C" void kernel_launch(void* const* d_in, const int* in_sizes, int n_in,
                              void* d_out, int out_size, void* d_ws, size_t ws_size,
                              hipStream_t stream) {
  const float* x = (const float*)d_in[0];
  const int* eidx = (const int*)d_in[1];
  const float* W = (const float*)d_in[2];
  const float* B = (const float*)d_in[3];
  float* out = (float*)d_out;

  int n = in_sizes[0] / 128;
  int e = in_sizes[1] / 2;
  int m = e + n;
  const int* src = eidx;
  const int* dstv = eidx + e;

  size_t off = 0;
  auto alloc = [&](size_t bytes) {
    size_t r = off;
    off += (bytes + 255) & ~(size_t)255;
    return r;
  };
  char* ws = (char*)d_ws;
  int* cnt = (int*)(ws + alloc((size_t)n * 4));
  unsigned short* rank = (unsigned short*)(ws + alloc((size_t)e * 2));
  int* row_ptr = (int*)(ws + alloc((size_t)(n + 1) * 4));
  int* bsum = (int*)(ws + alloc((size_t)1024 * 4));
  float* dinv = (float*)(ws + alloc((size_t)n * 4));
  uint2* cw = (uint2*)(ws + alloc((size_t)m * 8));
  unsigned short* p = (unsigned short*)(ws + alloc((size_t)n * 64 * 2));    // bf16 A*x_in
  unsigned short* h1 = (unsigned short*)(ws + alloc((size_t)n * 128 * 2));  // bf16 hidden
  unsigned short* q = (unsigned short*)(ws + alloc((size_t)n * 128 * 2));   // bf16 A*h1
  unsigned short* xb = (unsigned short*)(ws + alloc((size_t)n * 128 * 2));  // bf16 state mirror
  unsigned short* wt0 = (unsigned short*)(ws + alloc((size_t)4 * 8192 * 2));
  unsigned short* wt1 = (unsigned short*)(ws + alloc((size_t)4 * 8192 * 2));
  float* b0c = (float*)(ws + alloc((size_t)4 * 128 * 4));
  float* b1c = (float*)(ws + alloc((size_t)4 * 128 * 4));
  int gblk = (n + 63) / 64;
  float* partials = (float*)(ws + alloc((size_t)4 * gblk * 4));

  int total4 = n * 32;  // float4 elements of state
  int nb = (n + 1023) / 1024;
  hipMemsetAsync(cnt, 0, (size_t)n * 4, stream);
  init_out_kernel<<<(total4 + 255) / 256, 256, 0, stream>>>((const float4*)x, (float4*)out,
                                                            (uint2*)xb, total4);
  count_rank_kernel<<<(e + 255) / 256, 256, 0, stream>>>(dstv, cnt, rank, e);
  scan_blk_kernel<<<nb, 1024, 0, stream>>>(cnt, row_ptr, bsum, dinv, n);
  scan_top_kernel<<<1, 1024, 0, stream>>>(bsum, nb);
  scan_add_kernel<<<(n + 255) / 256, 256, 0, stream>>>(row_ptr, bsum, n, m);
  fill_kernel<<<(m + 255) / 256, 256, 0, stream>>>(src, dstv, rank, dinv, row_ptr, cnt, cw, e, n);
  prep_weights<<<256, 256, 0, stream>>>(W, B, wt0, wt1, b0c, b1c);

  const int hs_xin[4] = {0, 64, 0, 64};
  int pgrid = (n * 64 + 255) / 256;  // one wave per node
  for (int hsi = 0; hsi < 4; ++hsi) {
    int xin = hs_xin[hsi];
    int xout = 64 - xin;
    // p = A * x_in (64 feats): 8 lanes/row, 8 slots x 4 unroll = 32 edges/iter
    propagate_kernel<8, 4><<<pgrid, 256, 0, stream>>>(
        (const uint4*)xb, 16, xin / 8, (uint4*)p, 8, row_ptr, cw, n);
    gemm_layer0<<<gblk, 256, 0, stream>>>(p, wt0 + (size_t)hsi * 8192, b0c + hsi * 128, h1, n);
    // q = A * h1 (128 feats): 16 lanes/row, 4 slots x 4 unroll = 16 edges/iter
    propagate_kernel<16, 4><<<pgrid, 256, 0, stream>>>(
        (const uint4*)h1, 16, 0, (uint4*)q, 16, row_ptr, cw, n);
    gemm_final<<<gblk, 256, 0, stream>>>(q, wt1 + (size_t)hsi * 8192, b1c + hsi * 128, out, xb,
                                         xout, partials + (size_t)hsi * gblk, n);
  }
  ldj_reduce_kernel<<<1, 1024, 0, stream>>>(partials, 4 * gblk, out + total4 * 4);
}

// Round 9
// 365.084 us; speedup vs baseline: 1.6869x; 1.0996x over previous
//
#include <hip/hip_runtime.h>
#include <math.h>

// Graph normalizing flow on MI355X.
// State x (N x 128) fp32 lives in d_out; bf16 mirror xb for propagation gathers.
// ldj at d_out[N*128]. CSR-by-destination gather (packed col+weight uint2).
// A(hW)=(Ah)W rewrite: s/t GCN layer-0 share one 64-feat propagation.
// Dense layers: bf16 MFMA GEMMs, LDS-staged epilogues -> coalesced I/O.
// ldj: per-block non-atomic partials + one deterministic reduce kernel.
// CSR build: rank captured in count pass -> fill is atomic-free.
// Propagate: one wave/node, predicated constant-unroll gathers, launch_bounds(256,1).
// h1 hidden activations stored fp8 e4m3 -> 128-feat gather payload halves (256B->128B/row).

typedef __attribute__((ext_vector_type(8))) short bf16x8;
typedef __attribute__((ext_vector_type(4))) float f32x4;
typedef __attribute__((ext_vector_type(2))) float f32x2;

__device__ __forceinline__ float bf_lo(unsigned int u) { return __uint_as_float(u << 16); }
__device__ __forceinline__ float bf_hi(unsigned int u) { return __uint_as_float(u & 0xffff0000u); }
__device__ __forceinline__ unsigned short f2bf(float f) {
  unsigned int u = __float_as_uint(f);
  u = (u + 0x7fffu + ((u >> 16) & 1u)) >> 16;  // round-to-nearest-even
  return (unsigned short)u;
}
__device__ __forceinline__ unsigned int pack2(float a, float b) {
  return (unsigned int)f2bf(a) | ((unsigned int)f2bf(b) << 16);
}

// ---- fp8 e4m3 (values >= 0 only: h1 is post-relu) ----
#if __has_builtin(__builtin_amdgcn_cvt_pk_f32_fp8) && __has_builtin(__builtin_amdgcn_cvt_pk_fp8_f32)
#define FP8_HW 1
#else
#define FP8_HW 0
#endif

__device__ __forceinline__ void fp8x4_dec(unsigned int u, float* o) {
#if FP8_HW
  f32x2 lo = __builtin_amdgcn_cvt_pk_f32_fp8(u, false);
  f32x2 hi = __builtin_amdgcn_cvt_pk_f32_fp8(u, true);
  o[0] = lo[0]; o[1] = lo[1]; o[2] = hi[0]; o[3] = hi[1];
#else
#pragma unroll
  for (int k = 0; k < 4; ++k) {
    unsigned b = (u >> (k * 8)) & 0xff;
    unsigned e = (b >> 3) & 15, mn = b & 7;
    o[k] = e ? __uint_as_float(((e + 120) << 23) | (mn << 20)) : (float)mn * 0.001953125f;
  }
#endif
}

__device__ __forceinline__ unsigned int fp8_enc1(float f) {  // f >= 0
  f = fminf(f, 448.f);
  unsigned u = __float_as_uint(f);
  int e = (int)(u >> 23) - 127;
  if (e < -9) return 0u;
  if (e < -6) return (unsigned)__float2int_rn(f * 512.f);
  unsigned mant = u & 0x7fffffu;
  unsigned r = mant >> 20;
  unsigned rem = mant & 0xfffffu;
  if (rem > 0x80000u || (rem == 0x80000u && (r & 1))) r++;
  unsigned ef = (unsigned)(e + 7);
  if (r == 8) { r = 0; ef++; }
  if (ef > 15) { ef = 15; r = 7; }
  return (ef << 3) | r;
}

__device__ __forceinline__ unsigned int fp8x4_enc(float a, float b, float c, float d) {
#if FP8_HW
  unsigned int u = __builtin_amdgcn_cvt_pk_fp8_f32(a, b, 0u, false);
  u = __builtin_amdgcn_cvt_pk_fp8_f32(c, d, u, true);
  return u;
#else
  return fp8_enc1(a) | (fp8_enc1(b) << 8) | (fp8_enc1(c) << 16) | (fp8_enc1(d) << 24);
#endif
}

__global__ void init_out_kernel(const float4* __restrict__ x4, float4* __restrict__ out4,
                                uint2* __restrict__ xb2, int total4) {
  int i = blockIdx.x * blockDim.x + threadIdx.x;
  if (i < total4) {
    float4 v = x4[i];
    out4[i] = v;
    xb2[i] = make_uint2(pack2(v.x, v.y), pack2(v.z, v.w));
  }
}

// cnt must be zeroed (hipMemsetAsync). rank[i] = arrival order of edge i at its dst.
__global__ void count_rank_kernel(const int* __restrict__ dst, int* __restrict__ cnt,
                                  unsigned short* __restrict__ rank, int e) {
  int i = blockIdx.x * blockDim.x + threadIdx.x;
  if (i < e) rank[i] = (unsigned short)atomicAdd(&cnt[dst[i]], 1);
}

// --- parallel exclusive scan over (cnt[i]+1) [self-loop]; also emits dinv ---
__global__ void scan_blk_kernel(const int* __restrict__ cnt, int* __restrict__ row_ptr,
                                int* __restrict__ bsum, float* __restrict__ dinv, int n) {
  __shared__ int sdata[1024];
  int tid = threadIdx.x;
  int i = blockIdx.x * 1024 + tid;
  int v = (i < n) ? (cnt[i] + 1) : 0;
  if (i < n) dinv[i] = rsqrtf((float)v);
  sdata[tid] = v;
  __syncthreads();
  for (int d = 1; d < 1024; d <<= 1) {
    int t = (tid >= d) ? sdata[tid - d] : 0;
    __syncthreads();
    sdata[tid] += t;
    __syncthreads();
  }
  if (i < n) row_ptr[i] = sdata[tid] - v;  // exclusive within block
  if (tid == 1023) bsum[blockIdx.x] = sdata[1023];
}

__global__ void scan_top_kernel(int* __restrict__ bsum, int nb) {
  __shared__ int sdata[1024];
  int tid = threadIdx.x;
  int v = (tid < nb) ? bsum[tid] : 0;
  sdata[tid] = v;
  __syncthreads();
  for (int d = 1; d < 1024; d <<= 1) {
    int t = (tid >= d) ? sdata[tid - d] : 0;
    __syncthreads();
    sdata[tid] += t;
    __syncthreads();
  }
  if (tid < nb) bsum[tid] = sdata[tid] - v;  // exclusive block offsets
}

__global__ void scan_add_kernel(int* __restrict__ row_ptr, const int* __restrict__ bsum,
                                int n, int m) {
  int i = blockIdx.x * blockDim.x + threadIdx.x;
  if (i < n) row_ptr[i] += bsum[i >> 10];
  if (i == 0) row_ptr[n] = m;
}

// Atomic-free fill: edges land at row_ptr[d]+rank[i]; self-loop at last slot (cnt[v]).
__global__ void fill_kernel(const int* __restrict__ src, const int* __restrict__ dst,
                            const unsigned short* __restrict__ rank,
                            const float* __restrict__ dinv, const int* __restrict__ row_ptr,
                            const int* __restrict__ cnt, uint2* __restrict__ cw, int e, int n) {
  int i = blockIdx.x * blockDim.x + threadIdx.x;
  if (i < e) {
    int s = src[i], d = dst[i];
    int pos = row_ptr[d] + (int)rank[i];
    cw[pos] = make_uint2((unsigned)s, __float_as_uint(dinv[s] * dinv[d]));
  } else if (i < e + n) {
    int v = i - e;
    int pos = row_ptr[v] + cnt[v];
    float dv = dinv[v];
    cw[pos] = make_uint2((unsigned)v, __float_as_uint(dv * dv));
  }
}

// Build bf16 transposed weight mats + fp32 bias vectors for all 4 half-steps.
__global__ void prep_weights(const float* __restrict__ W, const float* __restrict__ B,
                             unsigned short* __restrict__ WT0, unsigned short* __restrict__ WT1,
                             float* __restrict__ b0c, float* __restrict__ b1c) {
  int idx = blockIdx.x * blockDim.x + threadIdx.x;
  if (idx < 65536) {
    int hsi = idx >> 14;
    int lay = (idx >> 13) & 1;
    int j = (idx >> 6) & 127;
    int k = idx & 63;
    int i = hsi >> 1, half = hsi & 1;
    int g = half * 4 + (j < 64 ? 0 : 2) + i;
    float v = W[(((size_t)g * 2 + lay) * 64 + k) * 64 + (j & 63)];
    unsigned short* dst = lay ? WT1 : WT0;
    dst[(size_t)hsi * 8192 + j * 64 + k] = f2bf(v);
  }
  if (idx < 1024) {
    int hsi = idx >> 8;
    int lay = (idx >> 7) & 1;
    int j = idx & 127;
    int i = hsi >> 1, half = hsi & 1;
    int g = half * 4 + (j < 64 ? 0 : 2) + i;
    (lay ? b1c : b0c)[hsi * 128 + j] = B[(g * 2 + lay) * 64 + (j & 63)];
  }
}

// One wave per node, bf16 input. LPR lanes/row (uint4: 8 -> 64 feats).
template <int LPR, int UNR>
__global__ __launch_bounds__(256, 1) void propagate_kernel(
    const uint4* __restrict__ X, int ldu4, int xoff4, uint4* __restrict__ Y, int ldy4,
    const int* __restrict__ row_ptr, const uint2* __restrict__ cw, int n) {
  constexpr int EPG = 64 / LPR;  // edge slots per wave
  int wid0 = (blockIdx.x * blockDim.x + threadIdx.x) >> 6;
  if (wid0 >= n) return;
  int wid = __builtin_amdgcn_readfirstlane(wid0);  // wave-uniform -> scalar loads
  int lane = threadIdx.x & 63;
  int eo = lane / LPR;
  int li = lane % LPR;
  int beg = row_ptr[wid], end = row_ptr[wid + 1];
  float a0 = 0.f, a1 = 0.f, a2 = 0.f, a3 = 0.f, a4 = 0.f, a5 = 0.f, a6 = 0.f, a7 = 0.f;
  for (int i = beg + eo; i < end; i += UNR * EPG) {
    uint2 ee[UNR];
    uint4 uu[UNR];
    float ww[UNR];
#pragma unroll
    for (int k = 0; k < UNR; ++k) {
      int idx = i + k * EPG;
      ee[k] = cw[idx < end ? idx : end - 1];
    }
#pragma unroll
    for (int k = 0; k < UNR; ++k) {
      int idx = i + k * EPG;
      ww[k] = (idx < end) ? __uint_as_float(ee[k].y) : 0.f;
      uu[k] = X[(size_t)ee[k].x * ldu4 + xoff4 + li];
    }
#pragma unroll
    for (int k = 0; k < UNR; ++k) {
      a0 += ww[k] * bf_lo(uu[k].x); a1 += ww[k] * bf_hi(uu[k].x);
      a2 += ww[k] * bf_lo(uu[k].y); a3 += ww[k] * bf_hi(uu[k].y);
      a4 += ww[k] * bf_lo(uu[k].z); a5 += ww[k] * bf_hi(uu[k].z);
      a6 += ww[k] * bf_lo(uu[k].w); a7 += ww[k] * bf_hi(uu[k].w);
    }
  }
#pragma unroll
  for (int ms = LPR; ms < 64; ms <<= 1) {
    a0 += __shfl_xor(a0, ms); a1 += __shfl_xor(a1, ms);
    a2 += __shfl_xor(a2, ms); a3 += __shfl_xor(a3, ms);
    a4 += __shfl_xor(a4, ms); a5 += __shfl_xor(a5, ms);
    a6 += __shfl_xor(a6, ms); a7 += __shfl_xor(a7, ms);
  }
  if (lane < LPR) {
    uint4 r;
    r.x = pack2(a0, a1);
    r.y = pack2(a2, a3);
    r.z = pack2(a4, a5);
    r.w = pack2(a6, a7);
    Y[(size_t)wid * ldy4 + li] = r;
  }
}

// fp8-input propagate: 128 feats/row as 16 uint2 (8B/lane), output bf16 q.
template <int UNR>
__global__ __launch_bounds__(256, 1) void propagate_fp8_kernel(
    const uint2* __restrict__ X, uint4* __restrict__ Y,
    const int* __restrict__ row_ptr, const uint2* __restrict__ cw, int n) {
  constexpr int LPR = 16, EPG = 4;
  int wid0 = (blockIdx.x * blockDim.x + threadIdx.x) >> 6;
  if (wid0 >= n) return;
  int wid = __builtin_amdgcn_readfirstlane(wid0);
  int lane = threadIdx.x & 63;
  int eo = lane / LPR;
  int li = lane % LPR;
  int beg = row_ptr[wid], end = row_ptr[wid + 1];
  float a0 = 0.f, a1 = 0.f, a2 = 0.f, a3 = 0.f, a4 = 0.f, a5 = 0.f, a6 = 0.f, a7 = 0.f;
  for (int i = beg + eo; i < end; i += UNR * EPG) {
    uint2 ee[UNR];
    uint2 uu[UNR];
    float ww[UNR];
#pragma unroll
    for (int k = 0; k < UNR; ++k) {
      int idx = i + k * EPG;
      ee[k] = cw[idx < end ? idx : end - 1];
    }
#pragma unroll
    for (int k = 0; k < UNR; ++k) {
      int idx = i + k * EPG;
      ww[k] = (idx < end) ? __uint_as_float(ee[k].y) : 0.f;
      uu[k] = X[(size_t)ee[k].x * 16 + li];
    }
#pragma unroll
    for (int k = 0; k < UNR; ++k) {
      float f[8];
      fp8x4_dec(uu[k].x, f);
      fp8x4_dec(uu[k].y, f + 4);
      a0 += ww[k] * f[0]; a1 += ww[k] * f[1];
      a2 += ww[k] * f[2]; a3 += ww[k] * f[3];
      a4 += ww[k] * f[4]; a5 += ww[k] * f[5];
      a6 += ww[k] * f[6]; a7 += ww[k] * f[7];
    }
  }
#pragma unroll
  for (int ms = LPR; ms < 64; ms <<= 1) {
    a0 += __shfl_xor(a0, ms); a1 += __shfl_xor(a1, ms);
    a2 += __shfl_xor(a2, ms); a3 += __shfl_xor(a3, ms);
    a4 += __shfl_xor(a4, ms); a5 += __shfl_xor(a5, ms);
    a6 += __shfl_xor(a6, ms); a7 += __shfl_xor(a7, ms);
  }
  if (lane < LPR) {
    uint4 r;
    r.x = pack2(a0, a1);
    r.y = pack2(a2, a3);
    r.z = pack2(a4, a5);
    r.w = pack2(a6, a7);
    Y[(size_t)wid * 16 + li] = r;
  }
}

// h1[r][j] = fp8(relu(p[r] @ Wcat0 + b0cat)). Phase1: MFMA -> LDS (bf16 tile).
// Phase2: convert to fp8, coalesced uint4 write-out (64x128 fp8 = 8KB/block).
__global__ __launch_bounds__(256) void gemm_layer0(const unsigned short* __restrict__ P,
                                                   const unsigned short* __restrict__ WT,
                                                   const float* __restrict__ bc,
                                                   unsigned char* __restrict__ H1, int n) {
  __shared__ unsigned short cs[64][136];
  int w = threadIdx.x >> 6, l = threadIdx.x & 63;
  int rbase0 = blockIdx.x * 64;
  int lr = l & 15, kg = l >> 4;
  int arow = rbase0 + w * 16 + lr;
  if (arow >= n) arow = n - 1;  // clamp; result discarded by guarded store
  const bf16x8* ap = (const bf16x8*)(P + (size_t)arow * 64);
  bf16x8 a0 = ap[kg];
  bf16x8 a1 = ap[kg + 4];
  f32x4 acc[8];
#pragma unroll
  for (int ct = 0; ct < 8; ++ct) {
    const bf16x8* bp = (const bf16x8*)(WT + (size_t)(ct * 16 + lr) * 64);
    f32x4 c = {0.f, 0.f, 0.f, 0.f};
    c = __builtin_amdgcn_mfma_f32_16x16x32_bf16(a0, bp[kg], c, 0, 0, 0);
    c = __builtin_amdgcn_mfma_f32_16x16x32_bf16(a1, bp[kg + 4], c, 0, 0, 0);
    acc[ct] = c;
  }
#pragma unroll
  for (int ct = 0; ct < 8; ++ct) {
    int colj = ct * 16 + lr;
    float bb = bc[colj];
#pragma unroll
    for (int i2 = 0; i2 < 4; ++i2) {
      int lrow = w * 16 + kg * 4 + i2;  // C/D: col=lane&15, row=(lane>>4)*4+reg
      cs[lrow][colj] = f2bf(fmaxf(acc[ct][i2] + bb, 0.f));
    }
  }
  __syncthreads();
  int row = threadIdx.x >> 2;
  int seg = threadIdx.x & 3;  // 32 values each
  if (rbase0 + row < n) {
    const uint4* lp = (const uint4*)&cs[row][seg * 32];
    unsigned int ou[8];
#pragma unroll
    for (int j = 0; j < 4; ++j) {
      uint4 v = lp[j];
      ou[j * 2] = fp8x4_enc(bf_lo(v.x), bf_hi(v.x), bf_lo(v.y), bf_hi(v.y));
      ou[j * 2 + 1] = fp8x4_enc(bf_lo(v.z), bf_hi(v.z), bf_lo(v.w), bf_hi(v.w));
    }
    uint4* dstp = (uint4*)(H1 + (size_t)(rbase0 + row) * 128 + seg * 32);
    dstp[0] = make_uint4(ou[0], ou[1], ou[2], ou[3]);
    dstp[1] = make_uint4(ou[4], ou[5], ou[6], ou[7]);
  }
}

// s=sigmoid(q[:,:64]@Ws1+bs), t=sigmoid(q[:,64:]@Wt1+bt).
// Phase1: MFMA + sigmoid -> LDS exp(s), t tiles; per-block ldj partial (NO atomics).
// Phase2: coalesced float4 RMW of Xout half + uint2 bf16-mirror stores.
__global__ __launch_bounds__(256) void gemm_final(const unsigned short* __restrict__ Q,
                                                  const unsigned short* __restrict__ WT,
                                                  const float* __restrict__ bc,
                                                  float* __restrict__ Xout,
                                                  unsigned short* __restrict__ Xb, int xoff,
                                                  float* __restrict__ partials, int n) {
  __shared__ float es[64][68];
  __shared__ float tv[64][68];
  __shared__ float redbuf[4];
  int w = threadIdx.x >> 6, l = threadIdx.x & 63;
  int rbase0 = blockIdx.x * 64;
  int lr = l & 15, kg = l >> 4;
  int arow = rbase0 + w * 16 + lr;
  if (arow >= n) arow = n - 1;
  const bf16x8* ap = (const bf16x8*)(Q + (size_t)arow * 128);
  bf16x8 as0 = ap[kg], as1 = ap[kg + 4];
  bf16x8 at0 = ap[kg + 8], at1 = ap[kg + 12];
  f32x4 acc[8];
#pragma unroll
  for (int ct = 0; ct < 8; ++ct) {
    const bf16x8* bp = (const bf16x8*)(WT + (size_t)(ct * 16 + lr) * 64);
    f32x4 c = {0.f, 0.f, 0.f, 0.f};
    bf16x8 x0 = (ct < 4) ? as0 : at0;
    bf16x8 x1 = (ct < 4) ? as1 : at1;
    c = __builtin_amdgcn_mfma_f32_16x16x32_bf16(x0, bp[kg], c, 0, 0, 0);
    c = __builtin_amdgcn_mfma_f32_16x16x32_bf16(x1, bp[kg + 4], c, 0, 0, 0);
    acc[ct] = c;
  }
  float wldj = 0.f;
#pragma unroll
  for (int ct = 0; ct < 4; ++ct) {
    int colj = ct * 16 + lr;
    float bs = bc[colj], bt = bc[colj + 64];
#pragma unroll
    for (int i2 = 0; i2 < 4; ++i2) {
      int lrow = w * 16 + kg * 4 + i2;
      float sv = 1.f / (1.f + __expf(-(acc[ct][i2] + bs)));
      float tvv = 1.f / (1.f + __expf(-(acc[ct + 4][i2] + bt)));
      es[lrow][colj] = __expf(sv);
      tv[lrow][colj] = tvv;
      if (rbase0 + lrow < n) wldj += sv;
    }
  }
#pragma unroll
  for (int off2 = 32; off2 > 0; off2 >>= 1) wldj += __shfl_down(wldj, off2);
  if (l == 0) redbuf[w] = wldj;
  __syncthreads();
  if (threadIdx.x == 0)
    partials[blockIdx.x] = redbuf[0] + redbuf[1] + redbuf[2] + redbuf[3];
  int row = threadIdx.x >> 2;
  int c0 = (threadIdx.x & 3) * 16;
  int grow = rbase0 + row;
  if (grow < n) {
    size_t base = (size_t)grow * 128 + xoff;
#pragma unroll
    for (int ci = 0; ci < 4; ++ci) {
      int c = c0 + ci * 4;
      float4 xv = *(const float4*)(Xout + base + c);
      float4 nv;
      nv.x = xv.x * es[row][c + 0] + tv[row][c + 0];
      nv.y = xv.y * es[row][c + 1] + tv[row][c + 1];
      nv.z = xv.z * es[row][c + 2] + tv[row][c + 2];
      nv.w = xv.w * es[row][c + 3] + tv[row][c + 3];
      *(float4*)(Xout + base + c) = nv;
      uint2 bb;
      bb.x = pack2(nv.x, nv.y);
      bb.y = pack2(nv.z, nv.w);
      *(uint2*)(Xb + base + c) = bb;
    }
  }
}

// Deterministic single-block sum of np partials -> *ldj_out (overwrite).
__global__ void ldj_reduce_kernel(const float* __restrict__ partials, int np,
                                  float* __restrict__ ldj_out) {
  __shared__ float sdata[1024];
  int tid = threadIdx.x;
  float a = 0.f;
  for (int i = tid; i < np; i += 1024) a += partials[i];
  sdata[tid] = a;
  __syncthreads();
  for (int d = 512; d > 0; d >>= 1) {
    if (tid < d) sdata[tid] += sdata[tid + d];
    __syncthreads();
  }
  if (tid == 0) *ldj_out = sdata[0];
}

extern "C" void kernel_launch(void* const* d_in, const int* in_sizes, int n_in,
                              void* d_out, int out_size, void* d_ws, size_t ws_size,
                              hipStream_t stream) {
  const float* x = (const float*)d_in[0];
  const int* eidx = (const int*)d_in[1];
  const float* W = (const float*)d_in[2];
  const float* B = (const float*)d_in[3];
  float* out = (float*)d_out;

  int n = in_sizes[0] / 128;
  int e = in_sizes[1] / 2;
  int m = e + n;
  const int* src = eidx;
  const int* dstv = eidx + e;

  size_t off = 0;
  auto alloc = [&](size_t bytes) {
    size_t r = off;
    off += (bytes + 255) & ~(size_t)255;
    return r;
  };
  char* ws = (char*)d_ws;
  int* cnt = (int*)(ws + alloc((size_t)n * 4));
  unsigned short* rank = (unsigned short*)(ws + alloc((size_t)e * 2));
  int* row_ptr = (int*)(ws + alloc((size_t)(n + 1) * 4));
  int* bsum = (int*)(ws + alloc((size_t)1024 * 4));
  float* dinv = (float*)(ws + alloc((size_t)n * 4));
  uint2* cw = (uint2*)(ws + alloc((size_t)m * 8));
  unsigned short* p = (unsigned short*)(ws + alloc((size_t)n * 64 * 2));    // bf16 A*x_in
  unsigned char* h1 = (unsigned char*)(ws + alloc((size_t)n * 128));        // fp8 hidden
  unsigned short* q = (unsigned short*)(ws + alloc((size_t)n * 128 * 2));   // bf16 A*h1
  unsigned short* xb = (unsigned short*)(ws + alloc((size_t)n * 128 * 2));  // bf16 state mirror
  unsigned short* wt0 = (unsigned short*)(ws + alloc((size_t)4 * 8192 * 2));
  unsigned short* wt1 = (unsigned short*)(ws + alloc((size_t)4 * 8192 * 2));
  float* b0c = (float*)(ws + alloc((size_t)4 * 128 * 4));
  float* b1c = (float*)(ws + alloc((size_t)4 * 128 * 4));
  int gblk = (n + 63) / 64;
  float* partials = (float*)(ws + alloc((size_t)4 * gblk * 4));

  int total4 = n * 32;  // float4 elements of state
  int nb = (n + 1023) / 1024;
  hipMemsetAsync(cnt, 0, (size_t)n * 4, stream);
  init_out_kernel<<<(total4 + 255) / 256, 256, 0, stream>>>((const float4*)x, (float4*)out,
                                                            (uint2*)xb, total4);
  count_rank_kernel<<<(e + 255) / 256, 256, 0, stream>>>(dstv, cnt, rank, e);
  scan_blk_kernel<<<nb, 1024, 0, stream>>>(cnt, row_ptr, bsum, dinv, n);
  scan_top_kernel<<<1, 1024, 0, stream>>>(bsum, nb);
  scan_add_kernel<<<(n + 255) / 256, 256, 0, stream>>>(row_ptr, bsum, n, m);
  fill_kernel<<<(m + 255) / 256, 256, 0, stream>>>(src, dstv, rank, dinv, row_ptr, cnt, cw, e, n);
  prep_weights<<<256, 256, 0, stream>>>(W, B, wt0, wt1, b0c, b1c);

  const int hs_xin[4] = {0, 64, 0, 64};
  int pgrid = (n * 64 + 255) / 256;  // one wave per node
  for (int hsi = 0; hsi < 4; ++hsi) {
    int xin = hs_xin[hsi];
    int xout = 64 - xin;
    // p = A * x_in (64 feats bf16): 8 lanes/row, 8 slots x 4 unroll
    propagate_kernel<8, 4><<<pgrid, 256, 0, stream>>>(
        (const uint4*)xb, 16, xin / 8, (uint4*)p, 8, row_ptr, cw, n);
    gemm_layer0<<<gblk, 256, 0, stream>>>(p, wt0 + (size_t)hsi * 8192, b0c + hsi * 128, h1, n);
    // q = A * h1 (128 feats fp8): 16 lanes/row, 4 slots x 4 unroll
    propagate_fp8_kernel<4><<<pgrid, 256, 0, stream>>>(
        (const uint2*)h1, (uint4*)q, row_ptr, cw, n);
    gemm_final<<<gblk, 256, 0, stream>>>(q, wt1 + (size_t)hsi * 8192, b1c + hsi * 128, out, xb,
                                         xout, partials + (size_t)hsi * gblk, n);
  }
  ldj_reduce_kernel<<<1, 1024, 0, stream>>>(partials, 4 * gblk, out + total4 * 4);
}

// Round 10
// 352.398 us; speedup vs baseline: 1.7476x; 1.0360x over previous
//
#include <hip/hip_runtime.h>
#include <math.h>

// Graph normalizing flow on MI355X.
// State x (N x 128) fp32 lives in d_out; PRESCALED bf16 mirror xb = dinv*x for gathers.
// ldj at d_out[N*128]. Weightless CSR: col-only (4B/edge); D^-1/2 A D^-1/2 X computed
// as dinv_dst * sum(prescaled rows). h1 hidden stored fp8 e4m3 prescaled by dinv.
// Dense layers: bf16 MFMA GEMMs (128-thread / 32-row blocks), LDS-staged epilogues.
// ldj: per-block non-atomic partials + deterministic reduce (atomics serialize!).
// CSR build: rank captured in count pass -> fill is atomic-free.
// Propagate: one wave/node, predicated constant-unroll gathers, launch_bounds(256,1).

typedef __attribute__((ext_vector_type(8))) short bf16x8;
typedef __attribute__((ext_vector_type(4))) float f32x4;
typedef __attribute__((ext_vector_type(2))) float f32x2;

__device__ __forceinline__ float bf_lo(unsigned int u) { return __uint_as_float(u << 16); }
__device__ __forceinline__ float bf_hi(unsigned int u) { return __uint_as_float(u & 0xffff0000u); }
__device__ __forceinline__ unsigned short f2bf(float f) {
  unsigned int u = __float_as_uint(f);
  u = (u + 0x7fffu + ((u >> 16) & 1u)) >> 16;  // round-to-nearest-even
  return (unsigned short)u;
}
__device__ __forceinline__ unsigned int pack2(float a, float b) {
  return (unsigned int)f2bf(a) | ((unsigned int)f2bf(b) << 16);
}

// ---- fp8 e4m3 (values >= 0 only: h1 is post-relu, prescaled) ----
#if __has_builtin(__builtin_amdgcn_cvt_pk_f32_fp8) && __has_builtin(__builtin_amdgcn_cvt_pk_fp8_f32)
#define FP8_HW 1
#else
#define FP8_HW 0
#endif

__device__ __forceinline__ void fp8x4_dec(unsigned int u, float* o) {
#if FP8_HW
  f32x2 lo = __builtin_amdgcn_cvt_pk_f32_fp8(u, false);
  f32x2 hi = __builtin_amdgcn_cvt_pk_f32_fp8(u, true);
  o[0] = lo[0]; o[1] = lo[1]; o[2] = hi[0]; o[3] = hi[1];
#else
#pragma unroll
  for (int k = 0; k < 4; ++k) {
    unsigned b = (u >> (k * 8)) & 0xff;
    unsigned e = (b >> 3) & 15, mn = b & 7;
    o[k] = e ? __uint_as_float(((e + 120) << 23) | (mn << 20)) : (float)mn * 0.001953125f;
  }
#endif
}

__device__ __forceinline__ unsigned int fp8_enc1(float f) {  // f >= 0
  f = fminf(f, 448.f);
  unsigned u = __float_as_uint(f);
  int e = (int)(u >> 23) - 127;
  if (e < -9) return 0u;
  if (e < -6) return (unsigned)__float2int_rn(f * 512.f);
  unsigned mant = u & 0x7fffffu;
  unsigned r = mant >> 20;
  unsigned rem = mant & 0xfffffu;
  if (rem > 0x80000u || (rem == 0x80000u && (r & 1))) r++;
  unsigned ef = (unsigned)(e + 7);
  if (r == 8) { r = 0; ef++; }
  if (ef > 15) { ef = 15; r = 7; }
  return (ef << 3) | r;
}

__device__ __forceinline__ unsigned int fp8x4_enc(float a, float b, float c, float d) {
#if FP8_HW
  unsigned int u = __builtin_amdgcn_cvt_pk_fp8_f32(a, b, 0u, false);
  u = __builtin_amdgcn_cvt_pk_fp8_f32(c, d, u, true);
  return u;
#else
  return fp8_enc1(a) | (fp8_enc1(b) << 8) | (fp8_enc1(c) << 16) | (fp8_enc1(d) << 24);
#endif
}

// out = x (fp32); xb = bf16(dinv[node] * x)  [prescaled mirror]. Runs after scan (dinv ready).
__global__ void init_out_kernel(const float4* __restrict__ x4, float4* __restrict__ out4,
                                uint2* __restrict__ xb2, const float* __restrict__ dinv,
                                int total4) {
  int i = blockIdx.x * blockDim.x + threadIdx.x;
  if (i < total4) {
    float4 v = x4[i];
    out4[i] = v;
    float dv = dinv[i >> 5];
    xb2[i] = make_uint2(pack2(v.x * dv, v.y * dv), pack2(v.z * dv, v.w * dv));
  }
}

// cnt must be zeroed (hipMemsetAsync). rank[i] = arrival order of edge i at its dst.
__global__ void count_rank_kernel(const int* __restrict__ dst, int* __restrict__ cnt,
                                  unsigned short* __restrict__ rank, int e) {
  int i = blockIdx.x * blockDim.x + threadIdx.x;
  if (i < e) rank[i] = (unsigned short)atomicAdd(&cnt[dst[i]], 1);
}

// --- parallel exclusive scan over (cnt[i]+1) [self-loop]; also emits dinv ---
__global__ void scan_blk_kernel(const int* __restrict__ cnt, int* __restrict__ row_ptr,
                                int* __restrict__ bsum, float* __restrict__ dinv, int n) {
  __shared__ int sdata[1024];
  int tid = threadIdx.x;
  int i = blockIdx.x * 1024 + tid;
  int v = (i < n) ? (cnt[i] + 1) : 0;
  if (i < n) dinv[i] = rsqrtf((float)v);
  sdata[tid] = v;
  __syncthreads();
  for (int d = 1; d < 1024; d <<= 1) {
    int t = (tid >= d) ? sdata[tid - d] : 0;
    __syncthreads();
    sdata[tid] += t;
    __syncthreads();
  }
  if (i < n) row_ptr[i] = sdata[tid] - v;  // exclusive within block
  if (tid == 1023) bsum[blockIdx.x] = sdata[1023];
}

__global__ void scan_top_kernel(int* __restrict__ bsum, int nb) {
  __shared__ int sdata[1024];
  int tid = threadIdx.x;
  int v = (tid < nb) ? bsum[tid] : 0;
  sdata[tid] = v;
  __syncthreads();
  for (int d = 1; d < 1024; d <<= 1) {
    int t = (tid >= d) ? sdata[tid - d] : 0;
    __syncthreads();
    sdata[tid] += t;
    __syncthreads();
  }
  if (tid < nb) bsum[tid] = sdata[tid] - v;  // exclusive block offsets
}

__global__ void scan_add_kernel(int* __restrict__ row_ptr, const int* __restrict__ bsum,
                                int n, int m) {
  int i = blockIdx.x * blockDim.x + threadIdx.x;
  if (i < n) row_ptr[i] += bsum[i >> 10];
  if (i == 0) row_ptr[n] = m;
}

// Atomic-free fill, col only (4B/edge): edges at row_ptr[d]+rank[i]; self-loop last.
__global__ void fill_kernel(const int* __restrict__ src, const int* __restrict__ dst,
                            const unsigned short* __restrict__ rank,
                            const int* __restrict__ row_ptr, const int* __restrict__ cnt,
                            int* __restrict__ col, int e, int n) {
  int i = blockIdx.x * blockDim.x + threadIdx.x;
  if (i < e) {
    col[row_ptr[dst[i]] + (int)rank[i]] = src[i];
  } else if (i < e + n) {
    int v = i - e;
    col[row_ptr[v] + cnt[v]] = v;
  }
}

// Build bf16 transposed weight mats + fp32 bias vectors for all 4 half-steps.
__global__ void prep_weights(const float* __restrict__ W, const float* __restrict__ B,
                             unsigned short* __restrict__ WT0, unsigned short* __restrict__ WT1,
                             float* __restrict__ b0c, float* __restrict__ b1c) {
  int idx = blockIdx.x * blockDim.x + threadIdx.x;
  if (idx < 65536) {
    int hsi = idx >> 14;
    int lay = (idx >> 13) & 1;
    int j = (idx >> 6) & 127;
    int k = idx & 63;
    int i = hsi >> 1, half = hsi & 1;
    int g = half * 4 + (j < 64 ? 0 : 2) + i;
    float v = W[(((size_t)g * 2 + lay) * 64 + k) * 64 + (j & 63)];
    unsigned short* dst = lay ? WT1 : WT0;
    dst[(size_t)hsi * 8192 + j * 64 + k] = f2bf(v);
  }
  if (idx < 1024) {
    int hsi = idx >> 8;
    int lay = (idx >> 7) & 1;
    int j = idx & 127;
    int i = hsi >> 1, half = hsi & 1;
    int g = half * 4 + (j < 64 ? 0 : 2) + i;
    (lay ? b1c : b0c)[hsi * 128 + j] = B[(g * 2 + lay) * 64 + (j & 63)];
  }
}

// One wave per node, bf16 prescaled input. LPR lanes/row (uint4: 8 -> 64 feats).
// Y[d] = dinv[d] * sum over col list. Predicated 0/1 mask, clamped duplicate loads.
template <int LPR, int UNR>
__global__ __launch_bounds__(256, 1) void propagate_kernel(
    const uint4* __restrict__ X, int ldu4, int xoff4, uint4* __restrict__ Y, int ldy4,
    const int* __restrict__ row_ptr, const int* __restrict__ col,
    const float* __restrict__ dinv, int n) {
  constexpr int EPG = 64 / LPR;  // edge slots per wave
  int wid0 = (blockIdx.x * blockDim.x + threadIdx.x) >> 6;
  if (wid0 >= n) return;
  int wid = __builtin_amdgcn_readfirstlane(wid0);  // wave-uniform -> scalar loads
  int lane = threadIdx.x & 63;
  int eo = lane / LPR;
  int li = lane % LPR;
  int beg = row_ptr[wid], end = row_ptr[wid + 1];
  float a0 = 0.f, a1 = 0.f, a2 = 0.f, a3 = 0.f, a4 = 0.f, a5 = 0.f, a6 = 0.f, a7 = 0.f;
  for (int i = beg + eo; i < end; i += UNR * EPG) {
    int cc[UNR];
    uint4 uu[UNR];
    float vv[UNR];
#pragma unroll
    for (int k = 0; k < UNR; ++k) {
      int idx = i + k * EPG;
      cc[k] = col[idx < end ? idx : end - 1];
    }
#pragma unroll
    for (int k = 0; k < UNR; ++k) {
      int idx = i + k * EPG;
      vv[k] = (idx < end) ? 1.f : 0.f;
      uu[k] = X[(size_t)cc[k] * ldu4 + xoff4 + li];
    }
#pragma unroll
    for (int k = 0; k < UNR; ++k) {
      a0 += vv[k] * bf_lo(uu[k].x); a1 += vv[k] * bf_hi(uu[k].x);
      a2 += vv[k] * bf_lo(uu[k].y); a3 += vv[k] * bf_hi(uu[k].y);
      a4 += vv[k] * bf_lo(uu[k].z); a5 += vv[k] * bf_hi(uu[k].z);
      a6 += vv[k] * bf_lo(uu[k].w); a7 += vv[k] * bf_hi(uu[k].w);
    }
  }
#pragma unroll
  for (int ms = LPR; ms < 64; ms <<= 1) {
    a0 += __shfl_xor(a0, ms); a1 += __shfl_xor(a1, ms);
    a2 += __shfl_xor(a2, ms); a3 += __shfl_xor(a3, ms);
    a4 += __shfl_xor(a4, ms); a5 += __shfl_xor(a5, ms);
    a6 += __shfl_xor(a6, ms); a7 += __shfl_xor(a7, ms);
  }
  if (lane < LPR) {
    float ds = dinv[wid];
    uint4 r;
    r.x = pack2(a0 * ds, a1 * ds);
    r.y = pack2(a2 * ds, a3 * ds);
    r.z = pack2(a4 * ds, a5 * ds);
    r.w = pack2(a6 * ds, a7 * ds);
    Y[(size_t)wid * ldy4 + li] = r;
  }
}

// fp8 prescaled input: 128 feats/row as 16 uint2 (8B/lane), output bf16 q = dinv[d]*sum.
template <int UNR>
__global__ __launch_bounds__(256, 1) void propagate_fp8_kernel(
    const uint2* __restrict__ X, uint4* __restrict__ Y, const int* __restrict__ row_ptr,
    const int* __restrict__ col, const float* __restrict__ dinv, int n) {
  constexpr int LPR = 16, EPG = 4;
  int wid0 = (blockIdx.x * blockDim.x + threadIdx.x) >> 6;
  if (wid0 >= n) return;
  int wid = __builtin_amdgcn_readfirstlane(wid0);
  int lane = threadIdx.x & 63;
  int eo = lane / LPR;
  int li = lane % LPR;
  int beg = row_ptr[wid], end = row_ptr[wid + 1];
  float a0 = 0.f, a1 = 0.f, a2 = 0.f, a3 = 0.f, a4 = 0.f, a5 = 0.f, a6 = 0.f, a7 = 0.f;
  for (int i = beg + eo; i < end; i += UNR * EPG) {
    int cc[UNR];
    uint2 uu[UNR];
    float vv[UNR];
#pragma unroll
    for (int k = 0; k < UNR; ++k) {
      int idx = i + k * EPG;
      cc[k] = col[idx < end ? idx : end - 1];
    }
#pragma unroll
    for (int k = 0; k < UNR; ++k) {
      int idx = i + k * EPG;
      vv[k] = (idx < end) ? 1.f : 0.f;
      uu[k] = X[(size_t)cc[k] * 16 + li];
    }
#pragma unroll
    for (int k = 0; k < UNR; ++k) {
      float f[8];
      fp8x4_dec(uu[k].x, f);
      fp8x4_dec(uu[k].y, f + 4);
      a0 += vv[k] * f[0]; a1 += vv[k] * f[1];
      a2 += vv[k] * f[2]; a3 += vv[k] * f[3];
      a4 += vv[k] * f[4]; a5 += vv[k] * f[5];
      a6 += vv[k] * f[6]; a7 += vv[k] * f[7];
    }
  }
#pragma unroll
  for (int ms = LPR; ms < 64; ms <<= 1) {
    a0 += __shfl_xor(a0, ms); a1 += __shfl_xor(a1, ms);
    a2 += __shfl_xor(a2, ms); a3 += __shfl_xor(a3, ms);
    a4 += __shfl_xor(a4, ms); a5 += __shfl_xor(a5, ms);
    a6 += __shfl_xor(a6, ms); a7 += __shfl_xor(a7, ms);
  }
  if (lane < LPR) {
    float ds = dinv[wid];
    uint4 r;
    r.x = pack2(a0 * ds, a1 * ds);
    r.y = pack2(a2 * ds, a3 * ds);
    r.z = pack2(a4 * ds, a5 * ds);
    r.w = pack2(a6 * ds, a7 * ds);
    Y[(size_t)wid * 16 + li] = r;
  }
}

// h1[r][j] = fp8(dinv[r] * relu(p[r] @ Wcat0 + b0cat)). 128 threads, 32 rows/block.
__global__ __launch_bounds__(128) void gemm_layer0(const unsigned short* __restrict__ P,
                                                   const unsigned short* __restrict__ WT,
                                                   const float* __restrict__ bc,
                                                   const float* __restrict__ dinv,
                                                   unsigned char* __restrict__ H1, int n) {
  __shared__ unsigned short cs[32][136];
  int w = threadIdx.x >> 6, l = threadIdx.x & 63;
  int rbase0 = blockIdx.x * 32;
  int lr = l & 15, kg = l >> 4;
  int arow = rbase0 + w * 16 + lr;
  if (arow >= n) arow = n - 1;  // clamp; result discarded by guarded store
  const bf16x8* ap = (const bf16x8*)(P + (size_t)arow * 64);
  bf16x8 a0 = ap[kg];
  bf16x8 a1 = ap[kg + 4];
  f32x4 acc[8];
#pragma unroll
  for (int ct = 0; ct < 8; ++ct) {
    const bf16x8* bp = (const bf16x8*)(WT + (size_t)(ct * 16 + lr) * 64);
    f32x4 c = {0.f, 0.f, 0.f, 0.f};
    c = __builtin_amdgcn_mfma_f32_16x16x32_bf16(a0, bp[kg], c, 0, 0, 0);
    c = __builtin_amdgcn_mfma_f32_16x16x32_bf16(a1, bp[kg + 4], c, 0, 0, 0);
    acc[ct] = c;
  }
#pragma unroll
  for (int ct = 0; ct < 8; ++ct) {
    int colj = ct * 16 + lr;
    float bb = bc[colj];
#pragma unroll
    for (int i2 = 0; i2 < 4; ++i2) {
      int lrow = w * 16 + kg * 4 + i2;  // C/D: col=lane&15, row=(lane>>4)*4+reg
      cs[lrow][colj] = f2bf(fmaxf(acc[ct][i2] + bb, 0.f));
    }
  }
  __syncthreads();
  int row = threadIdx.x >> 2;
  int seg = threadIdx.x & 3;  // 32 values each
  if (rbase0 + row < n) {
    float dr = dinv[rbase0 + row];
    const uint4* lp = (const uint4*)&cs[row][seg * 32];
    unsigned int ou[8];
#pragma unroll
    for (int j = 0; j < 4; ++j) {
      uint4 v = lp[j];
      ou[j * 2] = fp8x4_enc(dr * bf_lo(v.x), dr * bf_hi(v.x), dr * bf_lo(v.y), dr * bf_hi(v.y));
      ou[j * 2 + 1] = fp8x4_enc(dr * bf_lo(v.z), dr * bf_hi(v.z), dr * bf_lo(v.w), dr * bf_hi(v.w));
    }
    uint4* dstp = (uint4*)(H1 + (size_t)(rbase0 + row) * 128 + seg * 32);
    dstp[0] = make_uint4(ou[0], ou[1], ou[2], ou[3]);
    dstp[1] = make_uint4(ou[4], ou[5], ou[6], ou[7]);
  }
}

// s=sigmoid(q[:,:64]@Ws1+bs), t=sigmoid(q[:,64:]@Wt1+bt). 128 threads, 32 rows/block.
// Phase2: float4 RMW of Xout half + prescaled bf16-mirror stores; ldj partial.
__global__ __launch_bounds__(128) void gemm_final(const unsigned short* __restrict__ Q,
                                                  const unsigned short* __restrict__ WT,
                                                  const float* __restrict__ bc,
                                                  const float* __restrict__ dinv,
                                                  float* __restrict__ Xout,
                                                  unsigned short* __restrict__ Xb, int xoff,
                                                  float* __restrict__ partials, int n) {
  __shared__ float es[32][68];
  __shared__ float tv[32][68];
  __shared__ float redbuf[2];
  int w = threadIdx.x >> 6, l = threadIdx.x & 63;
  int rbase0 = blockIdx.x * 32;
  int lr = l & 15, kg = l >> 4;
  int arow = rbase0 + w * 16 + lr;
  if (arow >= n) arow = n - 1;
  const bf16x8* ap = (const bf16x8*)(Q + (size_t)arow * 128);
  bf16x8 as0 = ap[kg], as1 = ap[kg + 4];
  bf16x8 at0 = ap[kg + 8], at1 = ap[kg + 12];
  f32x4 acc[8];
#pragma unroll
  for (int ct = 0; ct < 8; ++ct) {
    const bf16x8* bp = (const bf16x8*)(WT + (size_t)(ct * 16 + lr) * 64);
    f32x4 c = {0.f, 0.f, 0.f, 0.f};
    bf16x8 x0 = (ct < 4) ? as0 : at0;
    bf16x8 x1 = (ct < 4) ? as1 : at1;
    c = __builtin_amdgcn_mfma_f32_16x16x32_bf16(x0, bp[kg], c, 0, 0, 0);
    c = __builtin_amdgcn_mfma_f32_16x16x32_bf16(x1, bp[kg + 4], c, 0, 0, 0);
    acc[ct] = c;
  }
  float wldj = 0.f;
#pragma unroll
  for (int ct = 0; ct < 4; ++ct) {
    int colj = ct * 16 + lr;
    float bs = bc[colj], bt = bc[colj + 64];
#pragma unroll
    for (int i2 = 0; i2 < 4; ++i2) {
      int lrow = w * 16 + kg * 4 + i2;
      float sv = 1.f / (1.f + __expf(-(acc[ct][i2] + bs)));
      float tvv = 1.f / (1.f + __expf(-(acc[ct + 4][i2] + bt)));
      es[lrow][colj] = __expf(sv);
      tv[lrow][colj] = tvv;
      if (rbase0 + lrow < n) wldj += sv;
    }
  }
#pragma unroll
  for (int off2 = 32; off2 > 0; off2 >>= 1) wldj += __shfl_down(wldj, off2);
  if (l == 0) redbuf[w] = wldj;
  __syncthreads();
  if (threadIdx.x == 0) partials[blockIdx.x] = redbuf[0] + redbuf[1];
  int row = threadIdx.x >> 2;
  int c0 = (threadIdx.x & 3) * 16;
  int grow = rbase0 + row;
  if (grow < n) {
    float dr = dinv[grow];
    size_t base = (size_t)grow * 128 + xoff;
#pragma unroll
    for (int ci = 0; ci < 4; ++ci) {
      int c = c0 + ci * 4;
      float4 xv = *(const float4*)(Xout + base + c);
      float4 nv;
      nv.x = xv.x * es[row][c + 0] + tv[row][c + 0];
      nv.y = xv.y * es[row][c + 1] + tv[row][c + 1];
      nv.z = xv.z * es[row][c + 2] + tv[row][c + 2];
      nv.w = xv.w * es[row][c + 3] + tv[row][c + 3];
      *(float4*)(Xout + base + c) = nv;
      uint2 bb;
      bb.x = pack2(nv.x * dr, nv.y * dr);
      bb.y = pack2(nv.z * dr, nv.w * dr);
      *(uint2*)(Xb + base + c) = bb;
    }
  }
}

// Deterministic single-block sum of np partials -> *ldj_out (overwrite).
__global__ void ldj_reduce_kernel(const float* __restrict__ partials, int np,
                                  float* __restrict__ ldj_out) {
  __shared__ float sdata[1024];
  int tid = threadIdx.x;
  float a = 0.f;
  for (int i = tid; i < np; i += 1024) a += partials[i];
  sdata[tid] = a;
  __syncthreads();
  for (int d = 512; d > 0; d >>= 1) {
    if (tid < d) sdata[tid] += sdata[tid + d];
    __syncthreads();
  }
  if (tid == 0) *ldj_out = sdata[0];
}

extern "C" void kernel_launch(void* const* d_in, const int* in_sizes, int n_in,
                              void* d_out, int out_size, void* d_ws, size_t ws_size,
                              hipStream_t stream) {
  const float* x = (const float*)d_in[0];
  const int* eidx = (const int*)d_in[1];
  const float* W = (const float*)d_in[2];
  const float* B = (const float*)d_in[3];
  float* out = (float*)d_out;

  int n = in_sizes[0] / 128;
  int e = in_sizes[1] / 2;
  int m = e + n;
  const int* src = eidx;
  const int* dstv = eidx + e;

  size_t off = 0;
  auto alloc = [&](size_t bytes) {
    size_t r = off;
    off += (bytes + 255) & ~(size_t)255;
    return r;
  };
  char* ws = (char*)d_ws;
  int* cnt = (int*)(ws + alloc((size_t)n * 4));
  unsigned short* rank = (unsigned short*)(ws + alloc((size_t)e * 2));
  int* row_ptr = (int*)(ws + alloc((size_t)(n + 1) * 4));
  int* bsum = (int*)(ws + alloc((size_t)1024 * 4));
  float* dinv = (float*)(ws + alloc((size_t)n * 4));
  int* col = (int*)(ws + alloc((size_t)m * 4));
  unsigned short* p = (unsigned short*)(ws + alloc((size_t)n * 64 * 2));    // bf16 A*x_in
  unsigned char* h1 = (unsigned char*)(ws + alloc((size_t)n * 128));        // fp8 hidden (prescaled)
  unsigned short* q = (unsigned short*)(ws + alloc((size_t)n * 128 * 2));   // bf16 A*h1
  unsigned short* xb = (unsigned short*)(ws + alloc((size_t)n * 128 * 2));  // bf16 prescaled state
  unsigned short* wt0 = (unsigned short*)(ws + alloc((size_t)4 * 8192 * 2));
  unsigned short* wt1 = (unsigned short*)(ws + alloc((size_t)4 * 8192 * 2));
  float* b0c = (float*)(ws + alloc((size_t)4 * 128 * 4));
  float* b1c = (float*)(ws + alloc((size_t)4 * 128 * 4));
  int gblk = (n + 31) / 32;
  float* partials = (float*)(ws + alloc((size_t)4 * gblk * 4));

  int total4 = n * 32;  // float4 elements of state
  int nb = (n + 1023) / 1024;
  hipMemsetAsync(cnt, 0, (size_t)n * 4, stream);
  count_rank_kernel<<<(e + 255) / 256, 256, 0, stream>>>(dstv, cnt, rank, e);
  scan_blk_kernel<<<nb, 1024, 0, stream>>>(cnt, row_ptr, bsum, dinv, n);
  scan_top_kernel<<<1, 1024, 0, stream>>>(bsum, nb);
  scan_add_kernel<<<(n + 255) / 256, 256, 0, stream>>>(row_ptr, bsum, n, m);
  init_out_kernel<<<(total4 + 255) / 256, 256, 0, stream>>>((const float4*)x, (float4*)out,
                                                            (uint2*)xb, dinv, total4);
  fill_kernel<<<(m + 255) / 256, 256, 0, stream>>>(src, dstv, rank, row_ptr, cnt, col, e, n);
  prep_weights<<<256, 256, 0, stream>>>(W, B, wt0, wt1, b0c, b1c);

  const int hs_xin[4] = {0, 64, 0, 64};
  int pgrid = (n * 64 + 255) / 256;  // one wave per node
  for (int hsi = 0; hsi < 4; ++hsi) {
    int xin = hs_xin[hsi];
    int xout = 64 - xin;
    // p = A~ * x_in (64 feats bf16 prescaled): 8 lanes/row, 8 slots x 4 unroll
    propagate_kernel<8, 4><<<pgrid, 256, 0, stream>>>(
        (const uint4*)xb, 16, xin / 8, (uint4*)p, 8, row_ptr, col, dinv, n);
    gemm_layer0<<<gblk, 128, 0, stream>>>(p, wt0 + (size_t)hsi * 8192, b0c + hsi * 128, dinv,
                                          h1, n);
    // q = A~ * h1 (128 feats fp8 prescaled): 16 lanes/row, 4 slots x 4 unroll
    propagate_fp8_kernel<4><<<pgrid, 256, 0, stream>>>(
        (const uint2*)h1, (uint4*)q, row_ptr, col, dinv, n);
    gemm_final<<<gblk, 128, 0, stream>>>(q, wt1 + (size_t)hsi * 8192, b1c + hsi * 128, dinv,
                                         out, xb, xout, partials + (size_t)hsi * gblk, n);
  }
  ldj_reduce_kernel<<<1, 1024, 0, stream>>>(partials, 4 * gblk, out + total4 * 4);
}